// Round 1
// 855.895 us; speedup vs baseline: 1.0206x; 1.0206x over previous
//
#include <hip/hip_runtime.h>
#include <cstddef>
#include <cstdint>

#define B_ 64
#define N_ 128
#define FIN_ 768
#define NEG_E_ (-9.0e15f)
#define NEG_S_ (-9.0e10f)
#define CHUNK_ 16

typedef unsigned short u16;
typedef unsigned int u32;
typedef float f32x4 __attribute__((ext_vector_type(4)));
typedef short s16x8 __attribute__((ext_vector_type(8)));   // 8 bf16 frag
typedef u16 u16x4 __attribute__((ext_vector_type(4)));

__device__ __forceinline__ u16 f2bf(float x) {
  u32 u = __float_as_uint(x);
  return (u16)((u + 0x7fffu + ((u >> 16) & 1u)) >> 16);
}
__device__ __forceinline__ float b2f(u16 h) {
  return __uint_as_float(((u32)h) << 16);
}

// ---------------------------------------------------------------------------
// Group pooling, k-sequential scan form (R7-verified). Full batch.
// ---------------------------------------------------------------------------
__global__ __launch_bounds__(128) void group_pool_kernel(
    const float* __restrict__ x, const int* __restrict__ offs,
    u16* __restrict__ xoh, u16* __restrict__ xol, int* __restrict__ ig)
{
  const int b = blockIdx.x;
  const int fc = blockIdx.y;
  const int tid = threadIdx.x;
  __shared__ int o0[N_], o1[N_];
  __shared__ int bnd[N_];
  __shared__ float invlen[N_];
  __shared__ int st[N_], en[N_];
  __shared__ int Gs;
  o0[tid] = offs[(b * N_ + tid) * 2 + 0];
  o1[tid] = offs[(b * N_ + tid) * 2 + 1];
  bnd[tid] = -1;
  __syncthreads();
  if (tid == 0) {
    int fz = N_;
    for (int k = 0; k < N_; ++k) { if (o0[k] == 0 && o1[k] == 0) { fz = k; break; } }
    int g = 0, prev = 0;
    for (int k = 0; k < fz; ++k) {
      int nxt = (k + 1 < N_) ? o0[k + 1] : 0;
      if (o1[k] == nxt - 1 && g < N_) {
        bnd[k] = g;
        invlen[g] = 1.0f / (float)(k + 1 - prev);
        st[g] = prev;
        en[g] = k + 1;
        prev = k + 1;
        ++g;
      }
    }
    Gs = g;
  }
  __syncthreads();
  const int G = Gs;
  const int f = fc * 128 + tid;
  const float* xb = x + (size_t)b * N_ * FIN_ + f;
  float acc = 0.0f;
  for (int k0 = 0; k0 < N_; k0 += 8) {
    float v[8];
#pragma unroll
    for (int u = 0; u < 8; ++u) v[u] = xb[(size_t)(k0 + u) * FIN_];
#pragma unroll
    for (int u = 0; u < 8; ++u) {
      acc += v[u];
      int g = bnd[k0 + u];
      if (g >= 0) {
        float mean = acc * invlen[g];
        u16 hh = f2bf(mean);
        size_t oo = ((size_t)b * N_ + g) * FIN_ + f;
        xoh[oo] = hh;
        xol[oo] = f2bf(mean - b2f(hh));
        acc = 0.0f;
      }
    }
  }
  for (int g = G; g < N_; ++g) {
    size_t oo = ((size_t)b * N_ + g) * FIN_ + f;
    xoh[oo] = 0;
    xol[oo] = 0;
  }
  if (fc == 0) {
    int g = tid;
    ig[(b * N_ + g) * 2 + 0] = (g < G) ? st[g] : 0;
    ig[(b * N_ + g) * 2 + 1] = (g < G) ? en[g] : 0;
  }
}

// ---------------------------------------------------------------------------
// Weight pack kernels: LDS-tiled transpose (32x32, +1 pad) -> coalesced
// reads AND writes.
// ---------------------------------------------------------------------------
__global__ __launch_bounds__(256) void pack_wgT(  // Wg_w[768][1024] -> WgT[1024][768]
    const float* __restrict__ w, u16* __restrict__ th, u16* __restrict__ tl)
{
  __shared__ float t[32][33];
  const int k0 = blockIdx.x * 32, n0 = blockIdx.y * 32;
  const int r = threadIdx.x >> 3;
  const int c = (threadIdx.x & 7) * 4;
  float4 v = *(const float4*)(w + (size_t)(k0 + r) * 1024 + n0 + c);
  t[r][c] = v.x; t[r][c + 1] = v.y; t[r][c + 2] = v.z; t[r][c + 3] = v.w;
  __syncthreads();
  u16x4 hv, lv;
#pragma unroll
  for (int i = 0; i < 4; ++i) {
    float xv = t[c + i][r];
    u16 h = f2bf(xv);
    hv[i] = h; lv[i] = f2bf(xv - b2f(h));
  }
  size_t dst = (size_t)(n0 + r) * 768 + k0 + c;
  *(u16x4*)(th + dst) = hv;
  *(u16x4*)(tl + dst) = lv;
}
__global__ __launch_bounds__(256) void pack_hwT(  // hW_w[8][1024][512] -> hWT[4096][1024]
    const float* __restrict__ w, u16* __restrict__ th, u16* __restrict__ tl)
{
  __shared__ float t[32][33];
  const int o0 = blockIdx.x * 32, f0 = blockIdx.y * 32, hd = blockIdx.z;
  const int r = threadIdx.x >> 3;
  const int c = (threadIdx.x & 7) * 4;
  float4 v = *(const float4*)(w + ((size_t)hd * 1024 + f0 + r) * 512 + o0 + c);
  t[r][c] = v.x; t[r][c + 1] = v.y; t[r][c + 2] = v.z; t[r][c + 3] = v.w;
  __syncthreads();
  u16x4 hv, lv;
#pragma unroll
  for (int i = 0; i < 4; ++i) {
    float xv = t[c + i][r];
    u16 h = f2bf(xv);
    hv[i] = h; lv[i] = f2bf(xv - b2f(h));
  }
  size_t dst = ((size_t)hd * 512 + o0 + r) * 1024 + f0 + c;
  *(u16x4*)(th + dst) = hv;
  *(u16x4*)(tl + dst) = lv;
}
__global__ __launch_bounds__(256) void pack_owT(  // oW_w[4096][512] -> oWT[512][4096]
    const float* __restrict__ w, u16* __restrict__ th, u16* __restrict__ tl)
{
  __shared__ float t[32][33];
  const int k0 = blockIdx.x * 32, o0 = blockIdx.y * 32;
  const int r = threadIdx.x >> 3;
  const int c = (threadIdx.x & 7) * 4;
  float4 v = *(const float4*)(w + (size_t)(k0 + r) * 512 + o0 + c);
  t[r][c] = v.x; t[r][c + 1] = v.y; t[r][c + 2] = v.z; t[r][c + 3] = v.w;
  __syncthreads();
  u16x4 hv, lv;
#pragma unroll
  for (int i = 0; i < 4; ++i) {
    float xv = t[c + i][r];
    u16 h = f2bf(xv);
    hv[i] = h; lv[i] = f2bf(xv - b2f(h));
  }
  size_t dst = (size_t)(o0 + r) * 4096 + k0 + c;
  *(u16x4*)(th + dst) = hv;
  *(u16x4*)(tl + dst) = lv;
}

// ---------------------------------------------------------------------------
// OLD split-bf16 MFMA GEMM (128x128, reg-prefetch 2-phase). Kept for the
// small-tile launches (x1T per-z, G7 split-K) where the big-tile kernel's
// grid would be too small.
// ---------------------------------------------------------------------------
__global__ __launch_bounds__(256) void mfma_split_gemm(
    const u16* __restrict__ Ah, const u16* __restrict__ Al,
    const u16* __restrict__ Bh, const u16* __restrict__ Bl,
    const float* __restrict__ bias, int bias_mode,   // 0 none, 1 per-n, 2 per-m
    u16* __restrict__ Oh, u16* __restrict__ Ol, float* __restrict__ Of,
    int out_f32, int do_elu,
    int K, int lda, int ldb,
    long long Az, long long Bz,
    int msh, long long s_mb, int nsh, long long s_nb, long long s_n,
    long long zb_s, long long zh_s, int zH)
{
  __shared__ u16 As_h[128][40];
  __shared__ u16 As_l[128][40];
  __shared__ u16 Bs_h[128][40];
  __shared__ u16 Bs_l[128][40];
  const int tid = threadIdx.x;
  const int wave = tid >> 6, lane = tid & 63;
  const int wm = (wave >> 1) * 64, wn = (wave & 1) * 64;
  const int bn = blockIdx.x * 128, bm = blockIdx.y * 128;
  const int z = blockIdx.z;
  const u16* Ahb = Ah + (long long)z * Az;
  const u16* Alb = Al + (long long)z * Az;
  const u16* Bhb = Bh + (long long)z * Bz;
  const u16* Blb = Bl + (long long)z * Bz;
  const int lm = lane & 15, lq = lane >> 4;

  const int sr = tid >> 1;
  const int sc = (tid & 1) * 16;
  const size_t ga = (size_t)(bm + sr) * lda + sc;
  const size_t gb = (size_t)(bn + sr) * ldb + sc;

  f32x4 acc[4][4];
#pragma unroll
  for (int i = 0; i < 4; ++i)
#pragma unroll
    for (int j = 0; j < 4; ++j) acc[i][j] = (f32x4){0.0f, 0.0f, 0.0f, 0.0f};

  uint4 r0, r1, r2, r3, r4, r5, r6, r7;
  r0 = *(const uint4*)(Ahb + ga);
  r1 = *(const uint4*)(Ahb + ga + 8);
  r2 = *(const uint4*)(Alb + ga);
  r3 = *(const uint4*)(Alb + ga + 8);
  r4 = *(const uint4*)(Bhb + gb);
  r5 = *(const uint4*)(Bhb + gb + 8);
  r6 = *(const uint4*)(Blb + gb);
  r7 = *(const uint4*)(Blb + gb + 8);

  for (int k0 = 0; k0 < K; k0 += 32) {
    __syncthreads();
    *(uint4*)&As_h[sr][sc] = r0;
    *(uint4*)&As_h[sr][sc + 8] = r1;
    *(uint4*)&As_l[sr][sc] = r2;
    *(uint4*)&As_l[sr][sc + 8] = r3;
    *(uint4*)&Bs_h[sr][sc] = r4;
    *(uint4*)&Bs_h[sr][sc + 8] = r5;
    *(uint4*)&Bs_l[sr][sc] = r6;
    *(uint4*)&Bs_l[sr][sc + 8] = r7;
    __syncthreads();
    int kn = k0 + 32;
    if (kn < K) {
      r0 = *(const uint4*)(Ahb + ga + kn);
      r1 = *(const uint4*)(Ahb + ga + kn + 8);
      r2 = *(const uint4*)(Alb + ga + kn);
      r3 = *(const uint4*)(Alb + ga + kn + 8);
      r4 = *(const uint4*)(Bhb + gb + kn);
      r5 = *(const uint4*)(Bhb + gb + kn + 8);
      r6 = *(const uint4*)(Blb + gb + kn);
      r7 = *(const uint4*)(Blb + gb + kn + 8);
    }
    s16x8 fa_h[4], fa_l[4], fb_h[4], fb_l[4];
#pragma unroll
    for (int t = 0; t < 4; ++t) {
      fa_h[t] = *(const s16x8*)&As_h[wm + t * 16 + lm][lq * 8];
      fa_l[t] = *(const s16x8*)&As_l[wm + t * 16 + lm][lq * 8];
      fb_h[t] = *(const s16x8*)&Bs_h[wn + t * 16 + lm][lq * 8];
      fb_l[t] = *(const s16x8*)&Bs_l[wn + t * 16 + lm][lq * 8];
    }
#pragma unroll
    for (int i = 0; i < 4; ++i)
#pragma unroll
      for (int j = 0; j < 4; ++j) {
        acc[i][j] = __builtin_amdgcn_mfma_f32_16x16x32_bf16(fa_h[i], fb_h[j], acc[i][j], 0, 0, 0);
        acc[i][j] = __builtin_amdgcn_mfma_f32_16x16x32_bf16(fa_h[i], fb_l[j], acc[i][j], 0, 0, 0);
        acc[i][j] = __builtin_amdgcn_mfma_f32_16x16x32_bf16(fa_l[i], fb_h[j], acc[i][j], 0, 0, 0);
      }
  }

  // ---- LDS-transpose epilogue ----
  __syncthreads();
  const long long zoff = (long long)(z / zH) * zb_s + (long long)(z % zH) * zh_s;
  const int mmask = (1 << msh) - 1;
  const int nmask = (1 << nsh) - 1;
  char* lds_raw = (char*)&As_h[0][0] + wave * 4608;
  const int rn = lane >> 2;
  const int rm = (lane & 3) * 16;

  if (out_f32) {
    float* slab = (float*)lds_raw;      // [16][68]
#pragma unroll
    for (int j = 0; j < 4; ++j) {
#pragma unroll
      for (int i = 0; i < 4; ++i) {
        int mb = bm + wm + i * 16 + lq * 4;
        int n = bn + wn + j * 16 + lm;
        f32x4 v = acc[i][j];
        if (bias_mode == 1) v += bias[n];
        else if (bias_mode == 2) { f32x4 b4 = *(const f32x4*)&bias[mb]; v += b4; }
        if (do_elu) {
          v.x = v.x > 0.0f ? v.x : expm1f(v.x);
          v.y = v.y > 0.0f ? v.y : expm1f(v.y);
          v.z = v.z > 0.0f ? v.z : expm1f(v.z);
          v.w = v.w > 0.0f ? v.w : expm1f(v.w);
        }
        *(f32x4*)&slab[lm * 68 + i * 16 + lq * 4] = v;
      }
      __syncthreads();
      int n = bn + wn + j * 16 + rn;
      int mbase = bm + wm + rm;
      long long off = (long long)(mbase >> msh) * s_mb + (mbase & mmask)
                    + (long long)(n >> nsh) * s_nb + (long long)(n & nmask) * s_n + zoff;
      const float* src = &slab[rn * 68 + rm];
      f32x4 v0 = *(const f32x4*)(src + 0);
      f32x4 v1 = *(const f32x4*)(src + 4);
      f32x4 v2 = *(const f32x4*)(src + 8);
      f32x4 v3 = *(const f32x4*)(src + 12);
      *(f32x4*)(Of + off + 0)  = v0;
      *(f32x4*)(Of + off + 4)  = v1;
      *(f32x4*)(Of + off + 8)  = v2;
      *(f32x4*)(Of + off + 12) = v3;
      __syncthreads();
    }
  } else {
    u16* slab_h = (u16*)lds_raw;        // [16][72]
    u16* slab_l = slab_h + 16 * 72;
#pragma unroll
    for (int j = 0; j < 4; ++j) {
#pragma unroll
      for (int i = 0; i < 4; ++i) {
        int mb = bm + wm + i * 16 + lq * 4;
        int n = bn + wn + j * 16 + lm;
        f32x4 v = acc[i][j];
        if (bias_mode == 1) v += bias[n];
        else if (bias_mode == 2) { f32x4 b4 = *(const f32x4*)&bias[mb]; v += b4; }
        if (do_elu) {
          v.x = v.x > 0.0f ? v.x : expm1f(v.x);
          v.y = v.y > 0.0f ? v.y : expm1f(v.y);
          v.z = v.z > 0.0f ? v.z : expm1f(v.z);
          v.w = v.w > 0.0f ? v.w : expm1f(v.w);
        }
        u16 h0 = f2bf(v.x), h1 = f2bf(v.y), h2 = f2bf(v.z), h3 = f2bf(v.w);
        u16x4 hv = {h0, h1, h2, h3};
        u16x4 lv = {f2bf(v.x - b2f(h0)), f2bf(v.y - b2f(h1)),
                    f2bf(v.z - b2f(h2)), f2bf(v.w - b2f(h3))};
        *(u16x4*)&slab_h[lm * 72 + i * 16 + lq * 4] = hv;
        *(u16x4*)&slab_l[lm * 72 + i * 16 + lq * 4] = lv;
      }
      __syncthreads();
      int n = bn + wn + j * 16 + rn;
      int mbase = bm + wm + rm;
      long long off = (long long)(mbase >> msh) * s_mb + (mbase & mmask)
                    + (long long)(n >> nsh) * s_nb + (long long)(n & nmask) * s_n + zoff;
      const u16* sh = &slab_h[rn * 72 + rm];
      const u16* sl = &slab_l[rn * 72 + rm];
      uint4 h0 = *(const uint4*)(sh + 0);
      uint4 h1 = *(const uint4*)(sh + 8);
      uint4 l0 = *(const uint4*)(sl + 0);
      uint4 l1 = *(const uint4*)(sl + 8);
      *(uint4*)(Oh + off + 0) = h0;
      *(uint4*)(Oh + off + 8) = h1;
      *(uint4*)(Ol + off + 0) = l0;
      *(uint4*)(Ol + off + 8) = l1;
      __syncthreads();
    }
  }
}

// ---------------------------------------------------------------------------
// NEW: 8-phase counted-vmcnt split-bf16 GEMM. BM=128, BN=256, BK=32,
// 8 waves (2Mx4N, 64x64 per wave). 3-deep LDS buffers (48KB each) staged by
// global_load_lds width=16 with pre-swizzled global source; hi|lo interleaved
// into 128B LDS rows with slot' = slot ^ (row&7) XOR swizzle (bank-uniform
// ds_read_b128). vmcnt(6) once per K-tile (2-deep prefetch, never 0 in
// steady state); per-phase s_barrier + lgkmcnt(0) + sched_barrier + setprio.
// ---------------------------------------------------------------------------
#define G8_BUF 49152   // 16KB A + 32KB B per buffer, 3 buffers

#define STAGE_A8(T) do { const int _t = (T); if (_t < nt) {                    \
    const int _q = _t % 3;                                                     \
    _Pragma("unroll")                                                          \
    for (int rg_ = 0; rg_ < 2; ++rg_) {                                        \
      const int r_ = wave * 16 + rg_ * 8 + srow;                               \
      const u16* s_ = Asel + (size_t)(bm + r_) * lda + _t * 32 + scol;         \
      __builtin_amdgcn_global_load_lds(                                        \
          (const __attribute__((address_space(1))) void*)s_,                   \
          (__attribute__((address_space(3))) void*)(ldsb + _q * G8_BUF +       \
              (wave * 16 + rg_ * 8) * 128),                                    \
          16, 0, 0);                                                           \
    } } } while (0)

#define STAGE_B8(T, RG0) do { const int _t = (T); if (_t < nt) {               \
    const int _q = _t % 3;                                                     \
    _Pragma("unroll")                                                          \
    for (int rg_ = (RG0); rg_ < (RG0) + 2; ++rg_) {                            \
      const int r_ = wave * 32 + rg_ * 8 + srow;                               \
      const u16* s_ = Bsel + (size_t)(bn + r_) * ldb + _t * 32 + scol;         \
      __builtin_amdgcn_global_load_lds(                                        \
          (const __attribute__((address_space(1))) void*)s_,                   \
          (__attribute__((address_space(3))) void*)(ldsb + _q * G8_BUF +       \
              16384 + (wave * 32 + rg_ * 8) * 128),                            \
          16, 0, 0);                                                           \
    } } } while (0)

#define GPHASE(J, STG) do {                                                    \
    s16x8 fb0 = *(const s16x8*)(Bbase + (J) * 2048 + hbyt);                    \
    s16x8 fb1 = *(const s16x8*)(Bbase + (J) * 2048 + lbyt);                    \
    STG;                                                                       \
    __builtin_amdgcn_s_barrier();                                              \
    asm volatile("s_waitcnt lgkmcnt(0)" ::: "memory");                         \
    __builtin_amdgcn_sched_barrier(0);                                         \
    __builtin_amdgcn_s_setprio(1);                                             \
    _Pragma("unroll")                                                          \
    for (int i_ = 0; i_ < 4; ++i_) {                                           \
      acc[i_][J] = __builtin_amdgcn_mfma_f32_16x16x32_bf16(fa[i_][0], fb0, acc[i_][J], 0, 0, 0); \
      acc[i_][J] = __builtin_amdgcn_mfma_f32_16x16x32_bf16(fa[i_][0], fb1, acc[i_][J], 0, 0, 0); \
      acc[i_][J] = __builtin_amdgcn_mfma_f32_16x16x32_bf16(fa[i_][1], fb0, acc[i_][J], 0, 0, 0); \
    }                                                                          \
    __builtin_amdgcn_s_setprio(0);                                             \
  } while (0)

__global__ __launch_bounds__(512) void mfma_split_gemm8(
    const u16* __restrict__ Ah, const u16* __restrict__ Al,
    const u16* __restrict__ Bh, const u16* __restrict__ Bl,
    const float* __restrict__ bias, int bias_mode,   // 1 per-n, 2 per-m
    u16* __restrict__ Oh, u16* __restrict__ Ol,
    int K, int lda, int ldb,
    int msh, long long s_mb, int nsh, long long s_nb, long long s_n)
{
  __shared__ __align__(128) char ldsb[3 * G8_BUF];   // 144 KB
  const int tid = threadIdx.x;
  const int wave = tid >> 6, lane = tid & 63;
  const int wm = (wave >> 2) * 64, wn = (wave & 3) * 64;
  const int bn = blockIdx.x * 256, bm = blockIdx.y * 128;
  const int lm = lane & 15, lq = lane >> 4;
  const int nt = K >> 5;

  // staging geometry: lane -> (row srow, phys slot); logical slot = phys ^ row
  const int srow = lane >> 3;
  const int sl = (lane & 7) ^ srow;          // logical slot this lane feeds
  const int scol = (sl & 3) * 8;             // k-offset (u16) within tile
  const u16* Asel = (sl < 4) ? Ah : Al;
  const u16* Bsel = (sl < 4) ? Bh : Bl;

  // read geometry: frag row r has r&7 == lm&7; hi slot lq -> phys lq^(lm&7)
  const int hbyt = (lq ^ (lm & 7)) * 16;
  const int lbyt = hbyt ^ 64;

  f32x4 acc[4][4];
#pragma unroll
  for (int i = 0; i < 4; ++i)
#pragma unroll
    for (int j = 0; j < 4; ++j) acc[i][j] = (f32x4){0.0f, 0.0f, 0.0f, 0.0f};

  // prologue: stage tiles 0 and 1
  STAGE_A8(0); STAGE_B8(0, 0); STAGE_B8(0, 2);
  STAGE_A8(1); STAGE_B8(1, 0); STAGE_B8(1, 2);
  if (nt > 1) asm volatile("s_waitcnt vmcnt(6)" ::: "memory");
  else        asm volatile("s_waitcnt vmcnt(0)" ::: "memory");
  __builtin_amdgcn_s_barrier();

  for (int t = 0; t < nt; ++t) {
    const int q = t % 3;
    const char* Abase = ldsb + q * G8_BUF + (wm + lm) * 128;
    const char* Bbase = ldsb + q * G8_BUF + 16384 + (wn + lm) * 128;
    s16x8 fa[4][2];
#pragma unroll
    for (int i = 0; i < 4; ++i) {
      fa[i][0] = *(const s16x8*)(Abase + i * 2048 + hbyt);
      fa[i][1] = *(const s16x8*)(Abase + i * 2048 + lbyt);
    }
    GPHASE(0, (void)0);
    __builtin_amdgcn_s_barrier();
    GPHASE(1, STAGE_A8(t + 2));
    __builtin_amdgcn_s_barrier();
    GPHASE(2, STAGE_B8(t + 2, 0));
    __builtin_amdgcn_s_barrier();
    GPHASE(3, STAGE_B8(t + 2, 2));
    if (t + 1 < nt) {
      if (t + 2 < nt) asm volatile("s_waitcnt vmcnt(6)" ::: "memory");
      else            asm volatile("s_waitcnt vmcnt(0)" ::: "memory");
      __builtin_amdgcn_s_barrier();
    }
  }

  // ---- LDS-transpose epilogue (split bf16 hi/lo out) ----
  __syncthreads();
  const int mmask = (1 << msh) - 1;
  const int nmask = (1 << nsh) - 1;
  char* lds_raw = ldsb + wave * 4608;
  const int rn = lane >> 2;
  const int rm = (lane & 3) * 16;
  u16* slab_h = (u16*)lds_raw;        // [16][72]
  u16* slab_l = slab_h + 16 * 72;
#pragma unroll
  for (int j = 0; j < 4; ++j) {
#pragma unroll
    for (int i = 0; i < 4; ++i) {
      int mb = bm + wm + i * 16 + lq * 4;
      int n = bn + wn + j * 16 + lm;
      f32x4 v = acc[i][j];
      if (bias_mode == 1) v += bias[n];
      else if (bias_mode == 2) { f32x4 b4 = *(const f32x4*)&bias[mb]; v += b4; }
      u16 h0 = f2bf(v.x), h1 = f2bf(v.y), h2 = f2bf(v.z), h3 = f2bf(v.w);
      u16x4 hv = {h0, h1, h2, h3};
      u16x4 lv = {f2bf(v.x - b2f(h0)), f2bf(v.y - b2f(h1)),
                  f2bf(v.z - b2f(h2)), f2bf(v.w - b2f(h3))};
      *(u16x4*)&slab_h[lm * 72 + i * 16 + lq * 4] = hv;
      *(u16x4*)&slab_l[lm * 72 + i * 16 + lq * 4] = lv;
    }
    __syncthreads();
    int n = bn + wn + j * 16 + rn;
    int mbase = bm + wm + rm;
    long long off = (long long)(mbase >> msh) * s_mb + (mbase & mmask)
                  + (long long)(n >> nsh) * s_nb + (long long)(n & nmask) * s_n;
    const u16* sh = &slab_h[rn * 72 + rm];
    const u16* slp = &slab_l[rn * 72 + rm];
    uint4 h0 = *(const uint4*)(sh + 0);
    uint4 h1 = *(const uint4*)(sh + 8);
    uint4 l0 = *(const uint4*)(slp + 0);
    uint4 l1 = *(const uint4*)(slp + 8);
    *(uint4*)(Oh + off + 0) = h0;
    *(uint4*)(Oh + off + 8) = h1;
    *(uint4*)(Ol + off + 0) = l0;
    *(uint4*)(Ol + off + 8) = l1;
    __syncthreads();
  }
}

// ---------------------------------------------------------------------------
// Split-K reduce for G7.
// ---------------------------------------------------------------------------
__global__ __launch_bounds__(256) void reduce4_bias(
    const float* __restrict__ ps, const float* __restrict__ bias,
    float* __restrict__ h2T, int col0)
{
  int base = (blockIdx.x * 256 + threadIdx.x) * 4;   // 512*2048 elements
  int o = base >> 11, m = base & 2047;
  f32x4 v = *(const f32x4*)(ps + base);
  v += *(const f32x4*)(ps + base + 1048576);
  v += *(const f32x4*)(ps + base + 2097152);
  v += *(const f32x4*)(ps + base + 3145728);
  v += bias[o];
  *(f32x4*)(h2T + (size_t)o * 8192 + col0 + m) = v;
}

// ---------------------------------------------------------------------------
// esrc/edst from hT (split bf16): block per (bc,head), 512 threads.
// ---------------------------------------------------------------------------
__global__ __launch_bounds__(512) void dot_pairs_hT(
    const u16* __restrict__ hTh, const u16* __restrict__ hTl,
    const float* __restrict__ W,   // ha_w [8][1024]
    float* __restrict__ esrc, float* __restrict__ edst)
{
  int bh = blockIdx.x;
  int head = bh & 7;
  int tid = threadIdx.x;
  int os = tid >> 7, i = tid & 127;
  const u16* ph = hTh + (size_t)bh * 65536 + (size_t)os * 16384 + i;
  const u16* pl = hTl + (size_t)bh * 65536 + (size_t)os * 16384 + i;
  const float* w1 = W + head * 1024 + os * 128;
  float s1 = 0.0f, s2 = 0.0f;
#pragma unroll 8
  for (int o = 0; o < 128; ++o) {
    float hv = b2f(ph[o * 128]) + b2f(pl[o * 128]);
    s1 = fmaf(hv, w1[o], s1);
    s2 = fmaf(hv, w1[512 + o], s2);
  }
  __shared__ float sh1[4][128], sh2[4][128];
  sh1[os][i] = s1;
  sh2[os][i] = s2;
  __syncthreads();
  if (os == 0) {
    esrc[bh * 128 + i] = sh1[0][i] + sh1[1][i] + sh1[2][i] + sh1[3][i];
    edst[bh * 128 + i] = sh2[0][i] + sh2[1][i] + sh2[2][i] + sh2[3][i];
  }
}

// e2 dots from h2T (fp32): block per b, 512 threads.
__global__ __launch_bounds__(512) void dot_pairs_h2T(
    const float* __restrict__ h2T, const float* __restrict__ oa,
    float* __restrict__ e2s, float* __restrict__ e2d)
{
  int b = blockIdx.x;
  int tid = threadIdx.x;
  int os = tid >> 7, i = tid & 127;
  const float* hb = h2T + (size_t)os * 128 * 8192 + b * 128 + i;
  const float* oa1 = oa + os * 128;
  float s1 = 0.0f, s2 = 0.0f;
#pragma unroll 8
  for (int o = 0; o < 128; ++o) {
    float hv = hb[(size_t)o * 8192];
    s1 = fmaf(hv, oa1[o], s1);
    s2 = fmaf(hv, oa1[512 + o], s2);
  }
  __shared__ float sh1[4][128], sh2[4][128];
  sh1[os][i] = s1;
  sh2[os][i] = s2;
  __syncthreads();
  if (os == 0) {
    e2s[b * 128 + i] = sh1[0][i] + sh1[1][i] + sh1[2][i] + sh1[3][i];
    e2d[b * 128 + i] = sh2[0][i] + sh2[1][i] + sh2[2][i] + sh2[3][i];
  }
}

// ---------------------------------------------------------------------------
// Edge softmax; split=1 -> bf16 hi/lo output, else fp32.  adj pre-offset.
// ---------------------------------------------------------------------------
__global__ __launch_bounds__(64) void edge_softmax_kernel(
    const float* __restrict__ esrc, const float* __restrict__ edst,
    const float* __restrict__ bias, const float* __restrict__ adj,
    float* __restrict__ attf, u16* __restrict__ atth, u16* __restrict__ attl,
    int H, int split)
{
  int row = blockIdx.x;
  int lane = threadIdx.x;
  int i = row & 127;
  int bh = row >> 7;
  int hd = bh % H;
  int b = bh / H;
  float es = esrc[row] + bias[hd];
  const float* adjr = adj + ((size_t)b * N_ + i) * N_;
  const float* edr = edst + (size_t)bh * N_;
  float v[2];
#pragma unroll
  for (int t = 0; t < 2; ++t) {
    int j = lane + t * 64;
    float e = es + edr[j];
    e = (e >= 0.0f) ? e : 0.2f * e;
    v[t] = (adjr[j] > 0.0f) ? e : NEG_E_;
  }
  float mx = fmaxf(v[0], v[1]);
  for (int off = 32; off; off >>= 1) mx = fmaxf(mx, __shfl_xor(mx, off));
  float e0 = expf(v[0] - mx), e1 = expf(v[1] - mx);
  float sm = e0 + e1;
  for (int off = 32; off; off >>= 1) sm += __shfl_xor(sm, off);
  float inv = 1.0f / sm;
  float p0 = e0 * inv, p1 = e1 * inv;
  size_t base = (size_t)row * N_;
  if (split) {
    u16 h0 = f2bf(p0), h1 = f2bf(p1);
    atth[base + lane] = h0;
    attl[base + lane] = f2bf(p0 - b2f(h0));
    atth[base + lane + 64] = h1;
    attl[base + lane + 64] = f2bf(p1 - b2f(h1));
  } else {
    attf[base + lane] = p0;
    attf[base + lane + 64] = p1;
  }
}

// ---------------------------------------------------------------------------
// Stage-2 fp32 batched GEMM + ELU (h2T[512][8192] B-layout).
// ---------------------------------------------------------------------------
__global__ __launch_bounds__(256) void bgemm_elu_bt_f32(
    const float* __restrict__ A, const float* __restrict__ BT,
    float* __restrict__ C)
{
  __shared__ float As[16][64];
  __shared__ float Bs[16][68];
  const int tid = threadIdx.x;
  const int tm = blockIdx.x >> 3, tn = blockIdx.x & 7;
  const int bm = tm * 64, bn = tn * 64;
  const int b = blockIdx.y;
  const float* Ab = A + (size_t)b * 16384;
  const float* BTb = BT + (size_t)b * 128;
  const int ty = tid >> 4, tx = tid & 15;
  const int ar = tid >> 2, ac = (tid & 3) * 4;
  float acc[4][4];
#pragma unroll
  for (int i = 0; i < 4; ++i)
#pragma unroll
    for (int j = 0; j < 4; ++j) acc[i][j] = 0.0f;

  for (int k0 = 0; k0 < 128; k0 += 16) {
    float4 av = *(const float4*)(Ab + (size_t)(bm + ar) * 128 + k0 + ac);
    float4 bv = *(const float4*)(BTb + (size_t)(bn + ar) * 8192 + k0 + ac);
    __syncthreads();
    As[ac + 0][ar] = av.x; As[ac + 1][ar] = av.y; As[ac + 2][ar] = av.z; As[ac + 3][ar] = av.w;
    Bs[ac + 0][ar] = bv.x; Bs[ac + 1][ar] = bv.y; Bs[ac + 2][ar] = bv.z; Bs[ac + 3][ar] = bv.w;
    __syncthreads();
#pragma unroll
    for (int kk = 0; kk < 16; ++kk) {
      float a[4], bb[4];
      *(float4*)a  = *(const float4*)&As[kk][ty * 4];
      *(float4*)bb = *(const float4*)&Bs[kk][tx * 4];
#pragma unroll
      for (int i = 0; i < 4; ++i)
#pragma unroll
        for (int j = 0; j < 4; ++j)
          acc[i][j] = fmaf(a[i], bb[j], acc[i][j]);
    }
  }
#pragma unroll
  for (int i = 0; i < 4; ++i) {
    int row = b * 128 + bm + ty * 4 + i;
    float4 v;
    v.x = acc[i][0] > 0.0f ? acc[i][0] : expm1f(acc[i][0]);
    v.y = acc[i][1] > 0.0f ? acc[i][1] : expm1f(acc[i][1]);
    v.z = acc[i][2] > 0.0f ? acc[i][2] : expm1f(acc[i][2]);
    v.w = acc[i][3] > 0.0f ? acc[i][3] : expm1f(acc[i][3]);
    *(float4*)(C + (size_t)row * 512 + bn + tx * 4) = v;
  }
}

// ---------------------------------------------------------------------------
// logits = x2 @ fin_w + fin_b  (one wave per row)
// ---------------------------------------------------------------------------
__global__ __launch_bounds__(256) void logits_kernel(
    const float* __restrict__ X, const float* __restrict__ w,
    const float* __restrict__ bptr, float* __restrict__ out, int R)
{
  int wv = (blockIdx.x * 256 + threadIdx.x) >> 6;
  int lane = threadIdx.x & 63;
  if (wv >= R) return;
  const float* xr = X + (size_t)wv * 512;
  float s = 0.0f;
#pragma unroll
  for (int i = 0; i < 8; ++i) {
    int c = lane + i * 64;
    s = fmaf(xr[c], w[c], s);
  }
  for (int off = 32; off; off >>= 1) s += __shfl_down(s, off);
  if (lane == 0) out[wv] = s + bptr[0];
}

// ---------------------------------------------------------------------------
// Final: scores -> stable rank -> gather fix -> expand.
// ---------------------------------------------------------------------------
__global__ __launch_bounds__(128) void finalize_kernel(
    const float* __restrict__ logits, const float* __restrict__ tag,
    const float* __restrict__ amask, const int* __restrict__ ig,
    int* __restrict__ out)
{
  const int b = blockIdx.x, tid = threadIdx.x;
  __shared__ float red[N_];
  __shared__ float scs[N_];
  __shared__ int fs[N_], fe[N_], lens[N_], csum[N_];
  __shared__ int redi[N_];

  float lg = logits[b * N_ + tid];
  float tg = tag[b * N_ + tid];
  float am = amask[b * N_ + tid];
  float m = (tg > 0.0f) ? am : 0.0f;

  float in1 = (m > 0.0f) ? lg * m : NEG_S_;
  red[tid] = in1; __syncthreads();
  for (int s = 64; s > 0; s >>= 1) { if (tid < s) red[tid] = fmaxf(red[tid], red[tid + s]); __syncthreads(); }
  float M1 = red[0]; __syncthreads();
  float e1 = expf(in1 - M1);
  red[tid] = e1; __syncthreads();
  for (int s = 64; s > 0; s >>= 1) { if (tid < s) red[tid] += red[tid + s]; __syncthreads(); }
  float S1 = red[0]; __syncthreads();
  float sc = e1 / S1;

  red[tid] = m; __syncthreads();
  for (int s = 64; s > 0; s >>= 1) { if (tid < s) red[tid] += red[tid + s]; __syncthreads(); }
  float SM = red[0]; __syncthreads();

  float in2 = (m > 0.0f) ? ((float)(N_ - tid) / SM) * m : NEG_S_;
  red[tid] = in2; __syncthreads();
  for (int s = 64; s > 0; s >>= 1) { if (tid < s) red[tid] = fmaxf(red[tid], red[tid + s]); __syncthreads(); }
  float M2 = red[0]; __syncthreads();
  float e2 = expf(in2 - M2);
  red[tid] = e2; __syncthreads();
  for (int s = 64; s > 0; s >>= 1) { if (tid < s) red[tid] += red[tid + s]; __syncthreads(); }
  float S2 = red[0]; __syncthreads();
  float ii = e2 / S2;

  scs[tid] = sc + ii;
  __syncthreads();

  float si = scs[tid];
  int rank = 0;
  for (int j = 0; j < N_; ++j) {
    float sj = scs[j];
    rank += (sj > si) || (sj == si && j < tid);
  }
  fs[tid] = ig[(b * N_ + rank) * 2 + 0];
  fe[tid] = ig[(b * N_ + rank) * 2 + 1];
  __syncthreads();

  redi[tid] = (fs[tid] == 0 && fe[tid] == 0) ? tid : N_;
  __syncthreads();
  for (int s = 64; s > 0; s >>= 1) { if (tid < s) redi[tid] = min(redi[tid], redi[tid + s]); __syncthreads(); }
  int fz = redi[0]; __syncthreads();
  lens[tid] = (tid < fz) ? (fe[tid] - fs[tid]) : 0;
  __syncthreads();
  if (tid == 0) {
    int r = 0;
    for (int k = 0; k < N_; ++k) { r += lens[k]; csum[k] = r; }
  }
  __syncthreads();
  int total = csum[N_ - 1];
  int l = tid;
  int k = 0;
  while (k < N_ && csum[k] <= l) ++k;
  if (k > N_ - 1) k = N_ - 1;
  int val = fs[k] + (l - (csum[k] - lens[k]));
  out[b * N_ + l] = (l < total) ? val : l;
}

// ---------------------------------------------------------------------------
extern "C" void kernel_launch(void* const* d_in, const int* in_sizes, int n_in,
                              void* d_out, int out_size, void* d_ws, size_t ws_size,
                              hipStream_t stream)
{
  const float* x     = (const float*)d_in[0];
  const float* tag   = (const float*)d_in[1];
  const int*   offs  = (const int*)  d_in[2];
  const float* amask = (const float*)d_in[3];
  const float* adj   = (const float*)d_in[4];
  const float* Wg_w  = (const float*)d_in[5];
  const float* Wg_b  = (const float*)d_in[6];
  const float* hW_w  = (const float*)d_in[7];
  const float* hW_b  = (const float*)d_in[8];
  const float* ha_w  = (const float*)d_in[9];
  const float* ha_b  = (const float*)d_in[10];
  const float* oW_w  = (const float*)d_in[11];
  const float* oW_b  = (const float*)d_in[12];
  const float* oa_w  = (const float*)d_in[13];
  const float* oa_b  = (const float*)d_in[14];
  const float* fin_w = (const float*)d_in[15];
  const float* fin_b = (const float*)d_in[16];
  int* out = (int*)d_out;

  // ---- workspace: 154.5 MB (< proven-safe 197.5 MB) ----
  char* ws = (char*)d_ws;
  size_t o = 0;
  int* ig     = (int*)(ws + o);  o += 131072;
  u16* WgT_h  = (u16*)(ws + o);  o += 1572864;
  u16* WgT_l  = (u16*)(ws + o);  o += 1572864;
  u16* hWT_h  = (u16*)(ws + o);  o += 8388608;
  u16* hWT_l  = (u16*)(ws + o);  o += 8388608;
  u16* oWT_h  = (u16*)(ws + o);  o += 4194304;
  u16* oWT_l  = (u16*)(ws + o);  o += 4194304;
  float* h2T  = (float*)(ws + o); o += 16777216;
  float* esrc = (float*)(ws + o); o += 65536;
  float* edst = (float*)(ws + o); o += 65536;
  float* e2s  = (float*)(ws + o); o += 32768;
  float* e2d  = (float*)(ws + o); o += 32768;
  float* lgts = (float*)(ws + o); o += 32768;
  u16* xw_h   = (u16*)(ws + o);  o += 16777216;   // full-batch xw (8192x1024)
  u16* xw_l   = (u16*)(ws + o);  o += 16777216;
  char* pool  = ws + o;          o += 75497472;   // overlaid region

  // pool overlays (time-sliced):
  u16* xoff_h = (u16*)(pool + 0);          // full-batch x_off (8192x768), dead after G2
  u16* xoff_l = (u16*)(pool + 12582912);
  u16* hT_h   = (u16*)(pool + 0);          // per-chunk hT (dead after x1T)
  u16* hT_l   = (u16*)(pool + 16777216);
  u16* x1_h   = (u16*)(pool + 33554432);   // per-chunk x1
  u16* x1_l   = (u16*)(pool + 50331648);
  u16* att_h  = (u16*)(pool + 67108864);   // per-chunk att
  u16* att_l  = (u16*)(pool + 71303168);
  float* ps   = (float*)(pool + 0);        // G7 split-K partials (overlays dead hT)
  float* att2 = (float*)(pool + 0);        // stage-2 tail
  float* x2   = (float*)(pool + 4194304);

  // weight packing (LDS-tiled transpose, coalesced both sides)
  pack_wgT<<<dim3(24, 32), 256, 0, stream>>>(Wg_w, WgT_h, WgT_l);
  pack_hwT<<<dim3(16, 32, 8), 256, 0, stream>>>(hW_w, hWT_h, hWT_l);
  pack_owT<<<dim3(128, 16), 256, 0, stream>>>(oW_w, oWT_h, oWT_l);

  // full-batch group pool -> x_off (split), ig
  group_pool_kernel<<<dim3(B_, 6), 128, 0, stream>>>(x, offs, xoff_h, xoff_l, ig);

  // G2 full-batch (swapped): xw[node][feat] = x_off @ Wg + Wg_b.
  // M=1024(feat), N=8192(node), K=768.  New 8-phase kernel: grid 32x8 = 256.
  mfma_split_gemm8<<<dim3(32, 8), 512, 0, stream>>>(
      WgT_h, WgT_l, xoff_h, xoff_l, Wg_b, 2,
      xw_h, xw_l,
      768, 768, 768,
      10, 0, 13, 0, 1024);

  for (int b0 = 0; b0 < B_; b0 += CHUNK_) {
    // G3: hT[(bc*8+h)*512+o][i] = (xw @ hW + hW_b)^T. M=2048,N=4096,K=1024.
    // New 8-phase kernel: grid 16x16 = 256 blocks.
    mfma_split_gemm8<<<dim3(16, 16), 512, 0, stream>>>(
        xw_h + (size_t)b0 * 131072, xw_l + (size_t)b0 * 131072,
        hWT_h, hWT_l, hW_b, 1,
        hT_h, hT_l,
        1024, 1024, 1024,
        7, 524288, 9, 65536, 128);

    dot_pairs_hT<<<CHUNK_ * 8, 512, 0, stream>>>(hT_h, hT_l, ha_w, esrc, edst);
    edge_softmax_kernel<<<CHUNK_ * 8 * 128, 64, 0, stream>>>(
        esrc, edst, ha_b, adj + (size_t)b0 * 16384, nullptr, att_h, att_l, 8, 1);

    // x1T: per z=(bc,h): M=512(o),N=128(i),K=128(j)
    mfma_split_gemm<<<dim3(1, 4, CHUNK_ * 8), 256, 0, stream>>>(
        hT_h, hT_l, att_h, att_l, nullptr, 0,
        x1_h, x1_l, nullptr, 0, 1,
        128, 128, 128, 65536, 16384,
        9, 0, 7, 0, 4096, 524288, 512, 8);

    // G7 (split-K=4): M=2048,N=512,K=1024/slice  (ps overlays dead hT)
    mfma_split_gemm<<<dim3(4, 16, 4), 256, 0, stream>>>(
        x1_h, x1_l, oWT_h, oWT_l, nullptr, 0,
        nullptr, nullptr, ps, 1, 0,
        1024, 4096, 4096, 1024, 1024,
        13, 0, 9, 0, 2048, 0, 1048576, 4);
    reduce4_bias<<<1024, 256, 0, stream>>>(ps, oW_b, h2T, b0 * 128);
  }

  // attention-2 (fp32, unchunked)
  dot_pairs_h2T<<<64, 512, 0, stream>>>(h2T, oa_w, e2s, e2d);
  edge_softmax_kernel<<<8192, 64, 0, stream>>>(e2s, e2d, oa_b, adj,
      att2, nullptr, nullptr, 1, 0);
  bgemm_elu_bt_f32<<<dim3(16, 64), 256, 0, stream>>>(att2, h2T, x2);

  // logits + finalize
  logits_kernel<<<2048, 256, 0, stream>>>(x2, fin_w, fin_b, lgts, 8192);
  finalize_kernel<<<B_, 128, 0, stream>>>(lgts, tag, amask, ig, out);
}

// Round 2
// 831.105 us; speedup vs baseline: 1.0511x; 1.0298x over previous
//
#include <hip/hip_runtime.h>
#include <cstddef>
#include <cstdint>

#define B_ 64
#define N_ 128
#define FIN_ 768
#define NEG_E_ (-9.0e15f)
#define NEG_S_ (-9.0e10f)
#define CHUNK_ 16

typedef unsigned short u16;
typedef unsigned int u32;
typedef float f32x4 __attribute__((ext_vector_type(4)));
typedef short s16x8 __attribute__((ext_vector_type(8)));   // 8 bf16 frag
typedef u16 u16x4 __attribute__((ext_vector_type(4)));

__device__ __forceinline__ u16 f2bf(float x) {
  u32 u = __float_as_uint(x);
  return (u16)((u + 0x7fffu + ((u >> 16) & 1u)) >> 16);
}
__device__ __forceinline__ float b2f(u16 h) {
  return __uint_as_float(((u32)h) << 16);
}

// ---------------------------------------------------------------------------
// Group pooling, k-sequential scan form (R7-verified). Full batch.
// ---------------------------------------------------------------------------
__global__ __launch_bounds__(128) void group_pool_kernel(
    const float* __restrict__ x, const int* __restrict__ offs,
    u16* __restrict__ xoh, u16* __restrict__ xol, int* __restrict__ ig)
{
  const int b = blockIdx.x;
  const int fc = blockIdx.y;
  const int tid = threadIdx.x;
  __shared__ int o0[N_], o1[N_];
  __shared__ int bnd[N_];
  __shared__ float invlen[N_];
  __shared__ int st[N_], en[N_];
  __shared__ int Gs;
  o0[tid] = offs[(b * N_ + tid) * 2 + 0];
  o1[tid] = offs[(b * N_ + tid) * 2 + 1];
  bnd[tid] = -1;
  __syncthreads();
  if (tid == 0) {
    int fz = N_;
    for (int k = 0; k < N_; ++k) { if (o0[k] == 0 && o1[k] == 0) { fz = k; break; } }
    int g = 0, prev = 0;
    for (int k = 0; k < fz; ++k) {
      int nxt = (k + 1 < N_) ? o0[k + 1] : 0;
      if (o1[k] == nxt - 1 && g < N_) {
        bnd[k] = g;
        invlen[g] = 1.0f / (float)(k + 1 - prev);
        st[g] = prev;
        en[g] = k + 1;
        prev = k + 1;
        ++g;
      }
    }
    Gs = g;
  }
  __syncthreads();
  const int G = Gs;
  const int f = fc * 128 + tid;
  const float* xb = x + (size_t)b * N_ * FIN_ + f;
  float acc = 0.0f;
  for (int k0 = 0; k0 < N_; k0 += 8) {
    float v[8];
#pragma unroll
    for (int u = 0; u < 8; ++u) v[u] = xb[(size_t)(k0 + u) * FIN_];
#pragma unroll
    for (int u = 0; u < 8; ++u) {
      acc += v[u];
      int g = bnd[k0 + u];
      if (g >= 0) {
        float mean = acc * invlen[g];
        u16 hh = f2bf(mean);
        size_t oo = ((size_t)b * N_ + g) * FIN_ + f;
        xoh[oo] = hh;
        xol[oo] = f2bf(mean - b2f(hh));
        acc = 0.0f;
      }
    }
  }
  for (int g = G; g < N_; ++g) {
    size_t oo = ((size_t)b * N_ + g) * FIN_ + f;
    xoh[oo] = 0;
    xol[oo] = 0;
  }
  if (fc == 0) {
    int g = tid;
    ig[(b * N_ + g) * 2 + 0] = (g < G) ? st[g] : 0;
    ig[(b * N_ + g) * 2 + 1] = (g < G) ? en[g] : 0;
  }
}

// ---------------------------------------------------------------------------
// Weight pack kernels: LDS-tiled transpose (32x32, +1 pad) -> coalesced
// reads AND writes.
// ---------------------------------------------------------------------------
__global__ __launch_bounds__(256) void pack_wgT(  // Wg_w[768][1024] -> WgT[1024][768]
    const float* __restrict__ w, u16* __restrict__ th, u16* __restrict__ tl)
{
  __shared__ float t[32][33];
  const int k0 = blockIdx.x * 32, n0 = blockIdx.y * 32;
  const int r = threadIdx.x >> 3;
  const int c = (threadIdx.x & 7) * 4;
  float4 v = *(const float4*)(w + (size_t)(k0 + r) * 1024 + n0 + c);
  t[r][c] = v.x; t[r][c + 1] = v.y; t[r][c + 2] = v.z; t[r][c + 3] = v.w;
  __syncthreads();
  u16x4 hv, lv;
#pragma unroll
  for (int i = 0; i < 4; ++i) {
    float xv = t[c + i][r];
    u16 h = f2bf(xv);
    hv[i] = h; lv[i] = f2bf(xv - b2f(h));
  }
  size_t dst = (size_t)(n0 + r) * 768 + k0 + c;
  *(u16x4*)(th + dst) = hv;
  *(u16x4*)(tl + dst) = lv;
}
__global__ __launch_bounds__(256) void pack_hwT(  // hW_w[8][1024][512] -> hWT[4096][1024]
    const float* __restrict__ w, u16* __restrict__ th, u16* __restrict__ tl)
{
  __shared__ float t[32][33];
  const int o0 = blockIdx.x * 32, f0 = blockIdx.y * 32, hd = blockIdx.z;
  const int r = threadIdx.x >> 3;
  const int c = (threadIdx.x & 7) * 4;
  float4 v = *(const float4*)(w + ((size_t)hd * 1024 + f0 + r) * 512 + o0 + c);
  t[r][c] = v.x; t[r][c + 1] = v.y; t[r][c + 2] = v.z; t[r][c + 3] = v.w;
  __syncthreads();
  u16x4 hv, lv;
#pragma unroll
  for (int i = 0; i < 4; ++i) {
    float xv = t[c + i][r];
    u16 h = f2bf(xv);
    hv[i] = h; lv[i] = f2bf(xv - b2f(h));
  }
  size_t dst = ((size_t)hd * 512 + o0 + r) * 1024 + f0 + c;
  *(u16x4*)(th + dst) = hv;
  *(u16x4*)(tl + dst) = lv;
}
__global__ __launch_bounds__(256) void pack_owT(  // oW_w[4096][512] -> oWT[512][4096]
    const float* __restrict__ w, u16* __restrict__ th, u16* __restrict__ tl)
{
  __shared__ float t[32][33];
  const int k0 = blockIdx.x * 32, o0 = blockIdx.y * 32;
  const int r = threadIdx.x >> 3;
  const int c = (threadIdx.x & 7) * 4;
  float4 v = *(const float4*)(w + (size_t)(k0 + r) * 512 + o0 + c);
  t[r][c] = v.x; t[r][c + 1] = v.y; t[r][c + 2] = v.z; t[r][c + 3] = v.w;
  __syncthreads();
  u16x4 hv, lv;
#pragma unroll
  for (int i = 0; i < 4; ++i) {
    float xv = t[c + i][r];
    u16 h = f2bf(xv);
    hv[i] = h; lv[i] = f2bf(xv - b2f(h));
  }
  size_t dst = (size_t)(o0 + r) * 4096 + k0 + c;
  *(u16x4*)(th + dst) = hv;
  *(u16x4*)(tl + dst) = lv;
}

// ---------------------------------------------------------------------------
// OLD split-bf16 MFMA GEMM (128x128, reg-prefetch 2-phase). Kept for the
// small-tile launches (x1T per-z, G7 split-K).
// ---------------------------------------------------------------------------
__global__ __launch_bounds__(256) void mfma_split_gemm(
    const u16* __restrict__ Ah, const u16* __restrict__ Al,
    const u16* __restrict__ Bh, const u16* __restrict__ Bl,
    const float* __restrict__ bias, int bias_mode,   // 0 none, 1 per-n, 2 per-m
    u16* __restrict__ Oh, u16* __restrict__ Ol, float* __restrict__ Of,
    int out_f32, int do_elu,
    int K, int lda, int ldb,
    long long Az, long long Bz,
    int msh, long long s_mb, int nsh, long long s_nb, long long s_n,
    long long zb_s, long long zh_s, int zH)
{
  __shared__ u16 As_h[128][40];
  __shared__ u16 As_l[128][40];
  __shared__ u16 Bs_h[128][40];
  __shared__ u16 Bs_l[128][40];
  const int tid = threadIdx.x;
  const int wave = tid >> 6, lane = tid & 63;
  const int wm = (wave >> 1) * 64, wn = (wave & 1) * 64;
  const int bn = blockIdx.x * 128, bm = blockIdx.y * 128;
  const int z = blockIdx.z;
  const u16* Ahb = Ah + (long long)z * Az;
  const u16* Alb = Al + (long long)z * Az;
  const u16* Bhb = Bh + (long long)z * Bz;
  const u16* Blb = Bl + (long long)z * Bz;
  const int lm = lane & 15, lq = lane >> 4;

  const int sr = tid >> 1;
  const int sc = (tid & 1) * 16;
  const size_t ga = (size_t)(bm + sr) * lda + sc;
  const size_t gb = (size_t)(bn + sr) * ldb + sc;

  f32x4 acc[4][4];
#pragma unroll
  for (int i = 0; i < 4; ++i)
#pragma unroll
    for (int j = 0; j < 4; ++j) acc[i][j] = (f32x4){0.0f, 0.0f, 0.0f, 0.0f};

  uint4 r0, r1, r2, r3, r4, r5, r6, r7;
  r0 = *(const uint4*)(Ahb + ga);
  r1 = *(const uint4*)(Ahb + ga + 8);
  r2 = *(const uint4*)(Alb + ga);
  r3 = *(const uint4*)(Alb + ga + 8);
  r4 = *(const uint4*)(Bhb + gb);
  r5 = *(const uint4*)(Bhb + gb + 8);
  r6 = *(const uint4*)(Blb + gb);
  r7 = *(const uint4*)(Blb + gb + 8);

  for (int k0 = 0; k0 < K; k0 += 32) {
    __syncthreads();
    *(uint4*)&As_h[sr][sc] = r0;
    *(uint4*)&As_h[sr][sc + 8] = r1;
    *(uint4*)&As_l[sr][sc] = r2;
    *(uint4*)&As_l[sr][sc + 8] = r3;
    *(uint4*)&Bs_h[sr][sc] = r4;
    *(uint4*)&Bs_h[sr][sc + 8] = r5;
    *(uint4*)&Bs_l[sr][sc] = r6;
    *(uint4*)&Bs_l[sr][sc + 8] = r7;
    __syncthreads();
    int kn = k0 + 32;
    if (kn < K) {
      r0 = *(const uint4*)(Ahb + ga + kn);
      r1 = *(const uint4*)(Ahb + ga + kn + 8);
      r2 = *(const uint4*)(Alb + ga + kn);
      r3 = *(const uint4*)(Alb + ga + kn + 8);
      r4 = *(const uint4*)(Bhb + gb + kn);
      r5 = *(const uint4*)(Bhb + gb + kn + 8);
      r6 = *(const uint4*)(Blb + gb + kn);
      r7 = *(const uint4*)(Blb + gb + kn + 8);
    }
    s16x8 fa_h[4], fa_l[4], fb_h[4], fb_l[4];
#pragma unroll
    for (int t = 0; t < 4; ++t) {
      fa_h[t] = *(const s16x8*)&As_h[wm + t * 16 + lm][lq * 8];
      fa_l[t] = *(const s16x8*)&As_l[wm + t * 16 + lm][lq * 8];
      fb_h[t] = *(const s16x8*)&Bs_h[wn + t * 16 + lm][lq * 8];
      fb_l[t] = *(const s16x8*)&Bs_l[wn + t * 16 + lm][lq * 8];
    }
#pragma unroll
    for (int i = 0; i < 4; ++i)
#pragma unroll
      for (int j = 0; j < 4; ++j) {
        acc[i][j] = __builtin_amdgcn_mfma_f32_16x16x32_bf16(fa_h[i], fb_h[j], acc[i][j], 0, 0, 0);
        acc[i][j] = __builtin_amdgcn_mfma_f32_16x16x32_bf16(fa_h[i], fb_l[j], acc[i][j], 0, 0, 0);
        acc[i][j] = __builtin_amdgcn_mfma_f32_16x16x32_bf16(fa_l[i], fb_h[j], acc[i][j], 0, 0, 0);
      }
  }

  // ---- LDS-transpose epilogue ----
  __syncthreads();
  const long long zoff = (long long)(z / zH) * zb_s + (long long)(z % zH) * zh_s;
  const int mmask = (1 << msh) - 1;
  const int nmask = (1 << nsh) - 1;
  char* lds_raw = (char*)&As_h[0][0] + wave * 4608;
  const int rn = lane >> 2;
  const int rm = (lane & 3) * 16;

  if (out_f32) {
    float* slab = (float*)lds_raw;      // [16][68]
#pragma unroll
    for (int j = 0; j < 4; ++j) {
#pragma unroll
      for (int i = 0; i < 4; ++i) {
        int mb = bm + wm + i * 16 + lq * 4;
        int n = bn + wn + j * 16 + lm;
        f32x4 v = acc[i][j];
        if (bias_mode == 1) v += bias[n];
        else if (bias_mode == 2) { f32x4 b4 = *(const f32x4*)&bias[mb]; v += b4; }
        if (do_elu) {
          v.x = v.x > 0.0f ? v.x : expm1f(v.x);
          v.y = v.y > 0.0f ? v.y : expm1f(v.y);
          v.z = v.z > 0.0f ? v.z : expm1f(v.z);
          v.w = v.w > 0.0f ? v.w : expm1f(v.w);
        }
        *(f32x4*)&slab[lm * 68 + i * 16 + lq * 4] = v;
      }
      __syncthreads();
      int n = bn + wn + j * 16 + rn;
      int mbase = bm + wm + rm;
      long long off = (long long)(mbase >> msh) * s_mb + (mbase & mmask)
                    + (long long)(n >> nsh) * s_nb + (long long)(n & nmask) * s_n + zoff;
      const float* src = &slab[rn * 68 + rm];
      f32x4 v0 = *(const f32x4*)(src + 0);
      f32x4 v1 = *(const f32x4*)(src + 4);
      f32x4 v2 = *(const f32x4*)(src + 8);
      f32x4 v3 = *(const f32x4*)(src + 12);
      *(f32x4*)(Of + off + 0)  = v0;
      *(f32x4*)(Of + off + 4)  = v1;
      *(f32x4*)(Of + off + 8)  = v2;
      *(f32x4*)(Of + off + 12) = v3;
      __syncthreads();
    }
  } else {
    u16* slab_h = (u16*)lds_raw;        // [16][72]
    u16* slab_l = slab_h + 16 * 72;
#pragma unroll
    for (int j = 0; j < 4; ++j) {
#pragma unroll
      for (int i = 0; i < 4; ++i) {
        int mb = bm + wm + i * 16 + lq * 4;
        int n = bn + wn + j * 16 + lm;
        f32x4 v = acc[i][j];
        if (bias_mode == 1) v += bias[n];
        else if (bias_mode == 2) { f32x4 b4 = *(const f32x4*)&bias[mb]; v += b4; }
        if (do_elu) {
          v.x = v.x > 0.0f ? v.x : expm1f(v.x);
          v.y = v.y > 0.0f ? v.y : expm1f(v.y);
          v.z = v.z > 0.0f ? v.z : expm1f(v.z);
          v.w = v.w > 0.0f ? v.w : expm1f(v.w);
        }
        u16 h0 = f2bf(v.x), h1 = f2bf(v.y), h2 = f2bf(v.z), h3 = f2bf(v.w);
        u16x4 hv = {h0, h1, h2, h3};
        u16x4 lv = {f2bf(v.x - b2f(h0)), f2bf(v.y - b2f(h1)),
                    f2bf(v.z - b2f(h2)), f2bf(v.w - b2f(h3))};
        *(u16x4*)&slab_h[lm * 72 + i * 16 + lq * 4] = hv;
        *(u16x4*)&slab_l[lm * 72 + i * 16 + lq * 4] = lv;
      }
      __syncthreads();
      int n = bn + wn + j * 16 + rn;
      int mbase = bm + wm + rm;
      long long off = (long long)(mbase >> msh) * s_mb + (mbase & mmask)
                    + (long long)(n >> nsh) * s_nb + (long long)(n & nmask) * s_n + zoff;
      const u16* sh = &slab_h[rn * 72 + rm];
      const u16* sl = &slab_l[rn * 72 + rm];
      uint4 h0 = *(const uint4*)(sh + 0);
      uint4 h1 = *(const uint4*)(sh + 8);
      uint4 l0 = *(const uint4*)(sl + 0);
      uint4 l1 = *(const uint4*)(sl + 8);
      *(uint4*)(Oh + off + 0) = h0;
      *(uint4*)(Oh + off + 8) = h1;
      *(uint4*)(Ol + off + 0) = l0;
      *(uint4*)(Ol + off + 8) = l1;
      __syncthreads();
    }
  }
}

// ---------------------------------------------------------------------------
// NEW (R2): flat counted-vmcnt split-bf16 GEMM. BM=128, BN=256, BK=32,
// 8 waves (2Mx4N, 64x64 per wave). 3-deep LDS buffers (48KB each) staged by
// global_load_lds width=16 with pre-swizzled global source; hi|lo interleaved
// into 128B LDS rows with slot' = slot ^ (row&7) XOR swizzle.
// NO per-phase barriers: reads of tile t hit buf t%3, loads for t+2 write
// buf (t+2)%3 -- the only hazard is cross-tile, covered by ONE vmcnt(6) +
// raw s_barrier + sched_barrier(0) per K-tile. Compiler pipelines
// ds_read<->MFMA with fine lgkmcnt (m97/r109 behavior); loads stay in
// flight across the barrier (AITER pattern, vmcnt never 0 in steady state).
// ---------------------------------------------------------------------------
#define G8_BUF 49152   // 16KB A + 32KB B per buffer, 3 buffers

#define STAGE_A8(T) do { const int _t = (T); if (_t < nt) {                    \
    const int _q = _t % 3;                                                     \
    _Pragma("unroll")                                                          \
    for (int rg_ = 0; rg_ < 2; ++rg_)                                          \
      __builtin_amdgcn_global_load_lds(                                        \
          (const __attribute__((address_space(1))) void*)(gA +                 \
              (size_t)_t * 32 + (size_t)rg_ * 8 * lda),                        \
          (__attribute__((address_space(3))) void*)(ldsAd + _q * G8_BUF +      \
              rg_ * 1024),                                                     \
          16, 0, 0);                                                           \
  } } while (0)

#define STAGE_B8(T) do { const int _t = (T); if (_t < nt) {                    \
    const int _q = _t % 3;                                                     \
    _Pragma("unroll")                                                          \
    for (int rg_ = 0; rg_ < 4; ++rg_)                                          \
      __builtin_amdgcn_global_load_lds(                                        \
          (const __attribute__((address_space(1))) void*)(gB +                 \
              (size_t)_t * 32 + (size_t)rg_ * 8 * ldb),                        \
          (__attribute__((address_space(3))) void*)(ldsBd + _q * G8_BUF +      \
              rg_ * 1024),                                                     \
          16, 0, 0);                                                           \
  } } while (0)

__global__ __launch_bounds__(512, 2) void mfma_split_gemm8(
    const u16* __restrict__ Ah, const u16* __restrict__ Al,
    const u16* __restrict__ Bh, const u16* __restrict__ Bl,
    const float* __restrict__ bias, int bias_mode,   // 1 per-n, 2 per-m
    u16* __restrict__ Oh, u16* __restrict__ Ol,
    int K, int lda, int ldb,
    int msh, long long s_mb, int nsh, long long s_nb, long long s_n)
{
  __shared__ __align__(128) char ldsb[3 * G8_BUF];   // 144 KB
  const int tid = threadIdx.x;
  const int wave = tid >> 6, lane = tid & 63;
  const int wm = (wave >> 2) * 64, wn = (wave & 3) * 64;
  const int bn = blockIdx.x * 256, bm = blockIdx.y * 128;
  const int lm = lane & 15, lq = lane >> 4;
  const int nt = K >> 5;

  // staging geometry: lane -> (row srow, phys slot); logical slot = phys ^ row
  const int srow = lane >> 3;
  const int sl = (lane & 7) ^ srow;          // logical slot this lane feeds
  const int scol = (sl & 3) * 8;             // k-offset (u16) within tile
  const u16* Asel = (sl < 4) ? Ah : Al;
  const u16* Bsel = (sl < 4) ? Bh : Bl;

  // hoisted per-wave staging bases
  const u16* gA = Asel + (size_t)(bm + wave * 16 + srow) * lda + scol;
  const u16* gB = Bsel + (size_t)(bn + wave * 32 + srow) * ldb + scol;
  char* ldsAd = ldsb + wave * 2048;            // A rows wave*16.., lane*16 added by HW
  char* ldsBd = ldsb + 16384 + wave * 4096;    // B rows wave*32..

  // read geometry: frag row r has r&7 == lm&7; hi slot lq -> phys lq^(lm&7)
  const int hbyt = (lq ^ (lm & 7)) * 16;
  const int lbyt = hbyt ^ 64;

  f32x4 acc[4][4];
#pragma unroll
  for (int i = 0; i < 4; ++i)
#pragma unroll
    for (int j = 0; j < 4; ++j) acc[i][j] = (f32x4){0.0f, 0.0f, 0.0f, 0.0f};

  // prologue: stage tiles 0 and 1 (FIFO: tile0's 6 loads first)
  STAGE_A8(0); STAGE_B8(0);
  STAGE_A8(1); STAGE_B8(1);
  if (nt > 1) asm volatile("s_waitcnt vmcnt(6)" ::: "memory");
  else        asm volatile("s_waitcnt vmcnt(0)" ::: "memory");
  __builtin_amdgcn_s_barrier();
  __builtin_amdgcn_sched_barrier(0);

#pragma unroll 3
  for (int t = 0; t < nt; ++t) {
    const int q = t % 3;
    // issue next-next tile's staging first (latency hiding)
    STAGE_A8(t + 2);
    STAGE_B8(t + 2);
    const char* Abase = ldsb + q * G8_BUF + (wm + lm) * 128;
    const char* Bbase = ldsb + q * G8_BUF + 16384 + (wn + lm) * 128;
    s16x8 fa[4][2], fb[4][2];
#pragma unroll
    for (int i = 0; i < 4; ++i) {
      fb[i][0] = *(const s16x8*)(Bbase + i * 2048 + hbyt);
      fb[i][1] = *(const s16x8*)(Bbase + i * 2048 + lbyt);
      fa[i][0] = *(const s16x8*)(Abase + i * 2048 + hbyt);
      fa[i][1] = *(const s16x8*)(Abase + i * 2048 + lbyt);
    }
    __builtin_amdgcn_s_setprio(1);
#pragma unroll
    for (int i = 0; i < 4; ++i)
#pragma unroll
      for (int j = 0; j < 4; ++j) {
        acc[i][j] = __builtin_amdgcn_mfma_f32_16x16x32_bf16(fa[i][0], fb[j][0], acc[i][j], 0, 0, 0);
        acc[i][j] = __builtin_amdgcn_mfma_f32_16x16x32_bf16(fa[i][0], fb[j][1], acc[i][j], 0, 0, 0);
        acc[i][j] = __builtin_amdgcn_mfma_f32_16x16x32_bf16(fa[i][1], fb[j][0], acc[i][j], 0, 0, 0);
      }
    __builtin_amdgcn_s_setprio(0);
    if (t + 1 < nt) {
      if (t + 2 < nt) asm volatile("s_waitcnt vmcnt(6)" ::: "memory");
      else            asm volatile("s_waitcnt vmcnt(0)" ::: "memory");
      __builtin_amdgcn_s_barrier();
      __builtin_amdgcn_sched_barrier(0);
    }
  }

  // ---- LDS-transpose epilogue (split bf16 hi/lo out) ----
  __syncthreads();
  const int mmask = (1 << msh) - 1;
  const int nmask = (1 << nsh) - 1;
  char* lds_raw = ldsb + wave * 4608;
  const int rn = lane >> 2;
  const int rm = (lane & 3) * 16;
  u16* slab_h = (u16*)lds_raw;        // [16][72]
  u16* slab_l = slab_h + 16 * 72;
#pragma unroll
  for (int j = 0; j < 4; ++j) {
#pragma unroll
    for (int i = 0; i < 4; ++i) {
      int mb = bm + wm + i * 16 + lq * 4;
      int n = bn + wn + j * 16 + lm;
      f32x4 v = acc[i][j];
      if (bias_mode == 1) v += bias[n];
      else if (bias_mode == 2) { f32x4 b4 = *(const f32x4*)&bias[mb]; v += b4; }
      u16 h0 = f2bf(v.x), h1 = f2bf(v.y), h2 = f2bf(v.z), h3 = f2bf(v.w);
      u16x4 hv = {h0, h1, h2, h3};
      u16x4 lv = {f2bf(v.x - b2f(h0)), f2bf(v.y - b2f(h1)),
                  f2bf(v.z - b2f(h2)), f2bf(v.w - b2f(h3))};
      *(u16x4*)&slab_h[lm * 72 + i * 16 + lq * 4] = hv;
      *(u16x4*)&slab_l[lm * 72 + i * 16 + lq * 4] = lv;
    }
    __syncthreads();
    int n = bn + wn + j * 16 + rn;
    int mbase = bm + wm + rm;
    long long off = (long long)(mbase >> msh) * s_mb + (mbase & mmask)
                  + (long long)(n >> nsh) * s_nb + (long long)(n & nmask) * s_n;
    const u16* sh = &slab_h[rn * 72 + rm];
    const u16* slp = &slab_l[rn * 72 + rm];
    uint4 h0 = *(const uint4*)(sh + 0);
    uint4 h1 = *(const uint4*)(sh + 8);
    uint4 l0 = *(const uint4*)(slp + 0);
    uint4 l1 = *(const uint4*)(slp + 8);
    *(uint4*)(Oh + off + 0) = h0;
    *(uint4*)(Oh + off + 8) = h1;
    *(uint4*)(Ol + off + 0) = l0;
    *(uint4*)(Ol + off + 8) = l1;
    __syncthreads();
  }
}

// ---------------------------------------------------------------------------
// Split-K reduce for G7.
// ---------------------------------------------------------------------------
__global__ __launch_bounds__(256) void reduce4_bias(
    const float* __restrict__ ps, const float* __restrict__ bias,
    float* __restrict__ h2T, int col0)
{
  int base = (blockIdx.x * 256 + threadIdx.x) * 4;   // 512*2048 elements
  int o = base >> 11, m = base & 2047;
  f32x4 v = *(const f32x4*)(ps + base);
  v += *(const f32x4*)(ps + base + 1048576);
  v += *(const f32x4*)(ps + base + 2097152);
  v += *(const f32x4*)(ps + base + 3145728);
  v += bias[o];
  *(f32x4*)(h2T + (size_t)o * 8192 + col0 + m) = v;
}

// ---------------------------------------------------------------------------
// esrc/edst from hT (split bf16): block per (bc,head), 512 threads.
// ---------------------------------------------------------------------------
__global__ __launch_bounds__(512) void dot_pairs_hT(
    const u16* __restrict__ hTh, const u16* __restrict__ hTl,
    const float* __restrict__ W,   // ha_w [8][1024]
    float* __restrict__ esrc, float* __restrict__ edst)
{
  int bh = blockIdx.x;
  int head = bh & 7;
  int tid = threadIdx.x;
  int os = tid >> 7, i = tid & 127;
  const u16* ph = hTh + (size_t)bh * 65536 + (size_t)os * 16384 + i;
  const u16* pl = hTl + (size_t)bh * 65536 + (size_t)os * 16384 + i;
  const float* w1 = W + head * 1024 + os * 128;
  float s1 = 0.0f, s2 = 0.0f;
#pragma unroll 8
  for (int o = 0; o < 128; ++o) {
    float hv = b2f(ph[o * 128]) + b2f(pl[o * 128]);
    s1 = fmaf(hv, w1[o], s1);
    s2 = fmaf(hv, w1[512 + o], s2);
  }
  __shared__ float sh1[4][128], sh2[4][128];
  sh1[os][i] = s1;
  sh2[os][i] = s2;
  __syncthreads();
  if (os == 0) {
    esrc[bh * 128 + i] = sh1[0][i] + sh1[1][i] + sh1[2][i] + sh1[3][i];
    edst[bh * 128 + i] = sh2[0][i] + sh2[1][i] + sh2[2][i] + sh2[3][i];
  }
}

// e2 dots from h2T (fp32): block per b, 512 threads.
__global__ __launch_bounds__(512) void dot_pairs_h2T(
    const float* __restrict__ h2T, const float* __restrict__ oa,
    float* __restrict__ e2s, float* __restrict__ e2d)
{
  int b = blockIdx.x;
  int tid = threadIdx.x;
  int os = tid >> 7, i = tid & 127;
  const float* hb = h2T + (size_t)os * 128 * 8192 + b * 128 + i;
  const float* oa1 = oa + os * 128;
  float s1 = 0.0f, s2 = 0.0f;
#pragma unroll 8
  for (int o = 0; o < 128; ++o) {
    float hv = hb[(size_t)o * 8192];
    s1 = fmaf(hv, oa1[o], s1);
    s2 = fmaf(hv, oa1[512 + o], s2);
  }
  __shared__ float sh1[4][128], sh2[4][128];
  sh1[os][i] = s1;
  sh2[os][i] = s2;
  __syncthreads();
  if (os == 0) {
    e2s[b * 128 + i] = sh1[0][i] + sh1[1][i] + sh1[2][i] + sh1[3][i];
    e2d[b * 128 + i] = sh2[0][i] + sh2[1][i] + sh2[2][i] + sh2[3][i];
  }
}

// ---------------------------------------------------------------------------
// Edge softmax; split=1 -> bf16 hi/lo output, else fp32.  adj pre-offset.
// ---------------------------------------------------------------------------
__global__ __launch_bounds__(64) void edge_softmax_kernel(
    const float* __restrict__ esrc, const float* __restrict__ edst,
    const float* __restrict__ bias, const float* __restrict__ adj,
    float* __restrict__ attf, u16* __restrict__ atth, u16* __restrict__ attl,
    int H, int split)
{
  int row = blockIdx.x;
  int lane = threadIdx.x;
  int i = row & 127;
  int bh = row >> 7;
  int hd = bh % H;
  int b = bh / H;
  float es = esrc[row] + bias[hd];
  const float* adjr = adj + ((size_t)b * N_ + i) * N_;
  const float* edr = edst + (size_t)bh * N_;
  float v[2];
#pragma unroll
  for (int t = 0; t < 2; ++t) {
    int j = lane + t * 64;
    float e = es + edr[j];
    e = (e >= 0.0f) ? e : 0.2f * e;
    v[t] = (adjr[j] > 0.0f) ? e : NEG_E_;
  }
  float mx = fmaxf(v[0], v[1]);
  for (int off = 32; off; off >>= 1) mx = fmaxf(mx, __shfl_xor(mx, off));
  float e0 = expf(v[0] - mx), e1 = expf(v[1] - mx);
  float sm = e0 + e1;
  for (int off = 32; off; off >>= 1) sm += __shfl_xor(sm, off);
  float inv = 1.0f / sm;
  float p0 = e0 * inv, p1 = e1 * inv;
  size_t base = (size_t)row * N_;
  if (split) {
    u16 h0 = f2bf(p0), h1 = f2bf(p1);
    atth[base + lane] = h0;
    attl[base + lane] = f2bf(p0 - b2f(h0));
    atth[base + lane + 64] = h1;
    attl[base + lane + 64] = f2bf(p1 - b2f(h1));
  } else {
    attf[base + lane] = p0;
    attf[base + lane + 64] = p1;
  }
}

// ---------------------------------------------------------------------------
// Stage-2 fp32 batched GEMM + ELU (h2T[512][8192] B-layout).
// ---------------------------------------------------------------------------
__global__ __launch_bounds__(256) void bgemm_elu_bt_f32(
    const float* __restrict__ A, const float* __restrict__ BT,
    float* __restrict__ C)
{
  __shared__ float As[16][64];
  __shared__ float Bs[16][68];
  const int tid = threadIdx.x;
  const int tm = blockIdx.x >> 3, tn = blockIdx.x & 7;
  const int bm = tm * 64, bn = tn * 64;
  const int b = blockIdx.y;
  const float* Ab = A + (size_t)b * 16384;
  const float* BTb = BT + (size_t)b * 128;
  const int ty = tid >> 4, tx = tid & 15;
  const int ar = tid >> 2, ac = (tid & 3) * 4;
  float acc[4][4];
#pragma unroll
  for (int i = 0; i < 4; ++i)
#pragma unroll
    for (int j = 0; j < 4; ++j) acc[i][j] = 0.0f;

  for (int k0 = 0; k0 < 128; k0 += 16) {
    float4 av = *(const float4*)(Ab + (size_t)(bm + ar) * 128 + k0 + ac);
    float4 bv = *(const float4*)(BTb + (size_t)(bn + ar) * 8192 + k0 + ac);
    __syncthreads();
    As[ac + 0][ar] = av.x; As[ac + 1][ar] = av.y; As[ac + 2][ar] = av.z; As[ac + 3][ar] = av.w;
    Bs[ac + 0][ar] = bv.x; Bs[ac + 1][ar] = bv.y; Bs[ac + 2][ar] = bv.z; Bs[ac + 3][ar] = bv.w;
    __syncthreads();
#pragma unroll
    for (int kk = 0; kk < 16; ++kk) {
      float a[4], bb[4];
      *(float4*)a  = *(const float4*)&As[kk][ty * 4];
      *(float4*)bb = *(const float4*)&Bs[kk][tx * 4];
#pragma unroll
      for (int i = 0; i < 4; ++i)
#pragma unroll
        for (int j = 0; j < 4; ++j)
          acc[i][j] = fmaf(a[i], bb[j], acc[i][j]);
    }
  }
#pragma unroll
  for (int i = 0; i < 4; ++i) {
    int row = b * 128 + bm + ty * 4 + i;
    float4 v;
    v.x = acc[i][0] > 0.0f ? acc[i][0] : expm1f(acc[i][0]);
    v.y = acc[i][1] > 0.0f ? acc[i][1] : expm1f(acc[i][1]);
    v.z = acc[i][2] > 0.0f ? acc[i][2] : expm1f(acc[i][2]);
    v.w = acc[i][3] > 0.0f ? acc[i][3] : expm1f(acc[i][3]);
    *(float4*)(C + (size_t)row * 512 + bn + tx * 4) = v;
  }
}

// ---------------------------------------------------------------------------
// logits = x2 @ fin_w + fin_b  (one wave per row)
// ---------------------------------------------------------------------------
__global__ __launch_bounds__(256) void logits_kernel(
    const float* __restrict__ X, const float* __restrict__ w,
    const float* __restrict__ bptr, float* __restrict__ out, int R)
{
  int wv = (blockIdx.x * 256 + threadIdx.x) >> 6;
  int lane = threadIdx.x & 63;
  if (wv >= R) return;
  const float* xr = X + (size_t)wv * 512;
  float s = 0.0f;
#pragma unroll
  for (int i = 0; i < 8; ++i) {
    int c = lane + i * 64;
    s = fmaf(xr[c], w[c], s);
  }
  for (int off = 32; off; off >>= 1) s += __shfl_down(s, off);
  if (lane == 0) out[wv] = s + bptr[0];
}

// ---------------------------------------------------------------------------
// Final: scores -> stable rank -> gather fix -> expand.
// ---------------------------------------------------------------------------
__global__ __launch_bounds__(128) void finalize_kernel(
    const float* __restrict__ logits, const float* __restrict__ tag,
    const float* __restrict__ amask, const int* __restrict__ ig,
    int* __restrict__ out)
{
  const int b = blockIdx.x, tid = threadIdx.x;
  __shared__ float red[N_];
  __shared__ float scs[N_];
  __shared__ int fs[N_], fe[N_], lens[N_], csum[N_];
  __shared__ int redi[N_];

  float lg = logits[b * N_ + tid];
  float tg = tag[b * N_ + tid];
  float am = amask[b * N_ + tid];
  float m = (tg > 0.0f) ? am : 0.0f;

  float in1 = (m > 0.0f) ? lg * m : NEG_S_;
  red[tid] = in1; __syncthreads();
  for (int s = 64; s > 0; s >>= 1) { if (tid < s) red[tid] = fmaxf(red[tid], red[tid + s]); __syncthreads(); }
  float M1 = red[0]; __syncthreads();
  float e1 = expf(in1 - M1);
  red[tid] = e1; __syncthreads();
  for (int s = 64; s > 0; s >>= 1) { if (tid < s) red[tid] += red[tid + s]; __syncthreads(); }
  float S1 = red[0]; __syncthreads();
  float sc = e1 / S1;

  red[tid] = m; __syncthreads();
  for (int s = 64; s > 0; s >>= 1) { if (tid < s) red[tid] += red[tid + s]; __syncthreads(); }
  float SM = red[0]; __syncthreads();

  float in2 = (m > 0.0f) ? ((float)(N_ - tid) / SM) * m : NEG_S_;
  red[tid] = in2; __syncthreads();
  for (int s = 64; s > 0; s >>= 1) { if (tid < s) red[tid] = fmaxf(red[tid], red[tid + s]); __syncthreads(); }
  float M2 = red[0]; __syncthreads();
  float e2 = expf(in2 - M2);
  red[tid] = e2; __syncthreads();
  for (int s = 64; s > 0; s >>= 1) { if (tid < s) red[tid] += red[tid + s]; __syncthreads(); }
  float S2 = red[0]; __syncthreads();
  float ii = e2 / S2;

  scs[tid] = sc + ii;
  __syncthreads();

  float si = scs[tid];
  int rank = 0;
  for (int j = 0; j < N_; ++j) {
    float sj = scs[j];
    rank += (sj > si) || (sj == si && j < tid);
  }
  fs[tid] = ig[(b * N_ + rank) * 2 + 0];
  fe[tid] = ig[(b * N_ + rank) * 2 + 1];
  __syncthreads();

  redi[tid] = (fs[tid] == 0 && fe[tid] == 0) ? tid : N_;
  __syncthreads();
  for (int s = 64; s > 0; s >>= 1) { if (tid < s) redi[tid] = min(redi[tid], redi[tid + s]); __syncthreads(); }
  int fz = redi[0]; __syncthreads();
  lens[tid] = (tid < fz) ? (fe[tid] - fs[tid]) : 0;
  __syncthreads();
  if (tid == 0) {
    int r = 0;
    for (int k = 0; k < N_; ++k) { r += lens[k]; csum[k] = r; }
  }
  __syncthreads();
  int total = csum[N_ - 1];
  int l = tid;
  int k = 0;
  while (k < N_ && csum[k] <= l) ++k;
  if (k > N_ - 1) k = N_ - 1;
  int val = fs[k] + (l - (csum[k] - lens[k]));
  out[b * N_ + l] = (l < total) ? val : l;
}

// ---------------------------------------------------------------------------
extern "C" void kernel_launch(void* const* d_in, const int* in_sizes, int n_in,
                              void* d_out, int out_size, void* d_ws, size_t ws_size,
                              hipStream_t stream)
{
  const float* x     = (const float*)d_in[0];
  const float* tag   = (const float*)d_in[1];
  const int*   offs  = (const int*)  d_in[2];
  const float* amask = (const float*)d_in[3];
  const float* adj   = (const float*)d_in[4];
  const float* Wg_w  = (const float*)d_in[5];
  const float* Wg_b  = (const float*)d_in[6];
  const float* hW_w  = (const float*)d_in[7];
  const float* hW_b  = (const float*)d_in[8];
  const float* ha_w  = (const float*)d_in[9];
  const float* ha_b  = (const float*)d_in[10];
  const float* oW_w  = (const float*)d_in[11];
  const float* oW_b  = (const float*)d_in[12];
  const float* oa_w  = (const float*)d_in[13];
  const float* oa_b  = (const float*)d_in[14];
  const float* fin_w = (const float*)d_in[15];
  const float* fin_b = (const float*)d_in[16];
  int* out = (int*)d_out;

  // ---- workspace: 154.5 MB (< proven-safe 197.5 MB) ----
  char* ws = (char*)d_ws;
  size_t o = 0;
  int* ig     = (int*)(ws + o);  o += 131072;
  u16* WgT_h  = (u16*)(ws + o);  o += 1572864;
  u16* WgT_l  = (u16*)(ws + o);  o += 1572864;
  u16* hWT_h  = (u16*)(ws + o);  o += 8388608;
  u16* hWT_l  = (u16*)(ws + o);  o += 8388608;
  u16* oWT_h  = (u16*)(ws + o);  o += 4194304;
  u16* oWT_l  = (u16*)(ws + o);  o += 4194304;
  float* h2T  = (float*)(ws + o); o += 16777216;
  float* esrc = (float*)(ws + o); o += 65536;
  float* edst = (float*)(ws + o); o += 65536;
  float* e2s  = (float*)(ws + o); o += 32768;
  float* e2d  = (float*)(ws + o); o += 32768;
  float* lgts = (float*)(ws + o); o += 32768;
  u16* xw_h   = (u16*)(ws + o);  o += 16777216;   // full-batch xw (8192x1024)
  u16* xw_l   = (u16*)(ws + o);  o += 16777216;
  char* pool  = ws + o;          o += 75497472;   // overlaid region

  // pool overlays (time-sliced):
  u16* xoff_h = (u16*)(pool + 0);          // full-batch x_off (8192x768), dead after G2
  u16* xoff_l = (u16*)(pool + 12582912);
  u16* hT_h   = (u16*)(pool + 0);          // per-chunk hT (dead after x1T)
  u16* hT_l   = (u16*)(pool + 16777216);
  u16* x1_h   = (u16*)(pool + 33554432);   // per-chunk x1
  u16* x1_l   = (u16*)(pool + 50331648);
  u16* att_h  = (u16*)(pool + 67108864);   // per-chunk att
  u16* att_l  = (u16*)(pool + 71303168);
  float* ps   = (float*)(pool + 0);        // G7 split-K partials (overlays dead hT)
  float* att2 = (float*)(pool + 0);        // stage-2 tail
  float* x2   = (float*)(pool + 4194304);

  // weight packing (LDS-tiled transpose, coalesced both sides)
  pack_wgT<<<dim3(24, 32), 256, 0, stream>>>(Wg_w, WgT_h, WgT_l);
  pack_hwT<<<dim3(16, 32, 8), 256, 0, stream>>>(hW_w, hWT_h, hWT_l);
  pack_owT<<<dim3(128, 16), 256, 0, stream>>>(oW_w, oWT_h, oWT_l);

  // full-batch group pool -> x_off (split), ig
  group_pool_kernel<<<dim3(B_, 6), 128, 0, stream>>>(x, offs, xoff_h, xoff_l, ig);

  // G2 full-batch (swapped): xw[node][feat] = x_off @ Wg + Wg_b.
  // M=1024(feat), N=8192(node), K=768.  Flat gemm8: grid 32x8 = 256.
  mfma_split_gemm8<<<dim3(32, 8), 512, 0, stream>>>(
      WgT_h, WgT_l, xoff_h, xoff_l, Wg_b, 2,
      xw_h, xw_l,
      768, 768, 768,
      10, 0, 13, 0, 1024);

  for (int b0 = 0; b0 < B_; b0 += CHUNK_) {
    // G3: hT[(bc*8+h)*512+o][i] = (xw @ hW + hW_b)^T. M=2048,N=4096,K=1024.
    // Flat gemm8: grid 16x16 = 256 blocks.
    mfma_split_gemm8<<<dim3(16, 16), 512, 0, stream>>>(
        xw_h + (size_t)b0 * 131072, xw_l + (size_t)b0 * 131072,
        hWT_h, hWT_l, hW_b, 1,
        hT_h, hT_l,
        1024, 1024, 1024,
        7, 524288, 9, 65536, 128);

    dot_pairs_hT<<<CHUNK_ * 8, 512, 0, stream>>>(hT_h, hT_l, ha_w, esrc, edst);
    edge_softmax_kernel<<<CHUNK_ * 8 * 128, 64, 0, stream>>>(
        esrc, edst, ha_b, adj + (size_t)b0 * 16384, nullptr, att_h, att_l, 8, 1);

    // x1T: per z=(bc,h): M=512(o),N=128(i),K=128(j)
    mfma_split_gemm<<<dim3(1, 4, CHUNK_ * 8), 256, 0, stream>>>(
        hT_h, hT_l, att_h, att_l, nullptr, 0,
        x1_h, x1_l, nullptr, 0, 1,
        128, 128, 128, 65536, 16384,
        9, 0, 7, 0, 4096, 524288, 512, 8);

    // G7 (split-K=4): M=2048,N=512,K=1024/slice  (ps overlays dead hT)
    mfma_split_gemm<<<dim3(4, 16, 4), 256, 0, stream>>>(
        x1_h, x1_l, oWT_h, oWT_l, nullptr, 0,
        nullptr, nullptr, ps, 1, 0,
        1024, 4096, 4096, 1024, 1024,
        13, 0, 9, 0, 2048, 0, 1048576, 4);
    reduce4_bias<<<1024, 256, 0, stream>>>(ps, oW_b, h2T, b0 * 128);
  }

  // attention-2 (fp32, unchunked)
  dot_pairs_h2T<<<64, 512, 0, stream>>>(h2T, oa_w, e2s, e2d);
  edge_softmax_kernel<<<8192, 64, 0, stream>>>(e2s, e2d, oa_b, adj,
      att2, nullptr, nullptr, 1, 0);
  bgemm_elu_bt_f32<<<dim3(16, 64), 256, 0, stream>>>(att2, h2T, x2);

  // logits + finalize
  logits_kernel<<<2048, 256, 0, stream>>>(x2, fin_w, fin_b, lgts, 8192);
  finalize_kernel<<<B_, 128, 0, stream>>>(lgts, tag, amask, ig, out);
}

// Round 3
// 802.136 us; speedup vs baseline: 1.0890x; 1.0361x over previous
//
#include <hip/hip_runtime.h>
#include <cstddef>
#include <cstdint>

#define B_ 64
#define N_ 128
#define FIN_ 768
#define NEG_E_ (-9.0e15f)
#define NEG_S_ (-9.0e10f)
#define CHUNK_ 16

typedef unsigned short u16;
typedef unsigned int u32;
typedef float f32x4 __attribute__((ext_vector_type(4)));
typedef short s16x8 __attribute__((ext_vector_type(8)));   // 8 bf16 frag
typedef u16 u16x4 __attribute__((ext_vector_type(4)));
typedef u16 u16x2 __attribute__((ext_vector_type(2)));

__device__ __forceinline__ u16 f2bf(float x) {
  u32 u = __float_as_uint(x);
  return (u16)((u + 0x7fffu + ((u >> 16) & 1u)) >> 16);
}
__device__ __forceinline__ float b2f(u16 h) {
  return __uint_as_float(((u32)h) << 16);
}

// ---------------------------------------------------------------------------
// Group pooling, R3 parallel form: groups are <=3 tokens (words are 1-3
// tokens), so after a parallel boundary scan each group mean is a direct
// sum of <=3 consecutive rows -- (group x feature)-parallel, same ascending-k
// summation order as the R7 scan form (bit-identical results).
// ---------------------------------------------------------------------------
__global__ __launch_bounds__(256) void group_pool_kernel(
    const float* __restrict__ x, const int* __restrict__ offs,
    u16* __restrict__ xoh, u16* __restrict__ xol, int* __restrict__ ig)
{
  const int b = blockIdx.x;
  const int fc = blockIdx.y;          // 6 chunks of 128 features
  const int tid = threadIdx.x;
  __shared__ int o0[N_ + 1], o1[N_];
  __shared__ int bi[N_], cs[N_];
  __shared__ int st[N_], en[N_];
  __shared__ float invlen[N_];
  __shared__ int fzs;

  if (tid < N_) {
    o0[tid] = offs[(b * N_ + tid) * 2 + 0];
    o1[tid] = offs[(b * N_ + tid) * 2 + 1];
  }
  if (tid == 0) { o0[N_] = 0; fzs = N_; }
  __syncthreads();
  if (tid < N_ && o0[tid] == 0 && o1[tid] == 0) atomicMin(&fzs, tid);
  __syncthreads();
  const int fz = fzs;
  if (tid < N_) {
    int nxt = o0[tid + 1];
    bi[tid] = (tid < fz && o1[tid] == nxt - 1) ? 1 : 0;
    cs[tid] = bi[tid];
  }
  __syncthreads();
  // Hillis-Steele inclusive scan over 128 elements
  for (int d = 1; d < N_; d <<= 1) {
    int v = 0;
    if (tid < N_ && tid >= d) v = cs[tid - d];
    __syncthreads();
    if (tid < N_) cs[tid] += v;
    __syncthreads();
  }
  if (tid < N_ && bi[tid]) en[cs[tid] - 1] = tid + 1;
  __syncthreads();
  const int G = cs[N_ - 1];
  if (tid < G) {
    int s = tid ? en[tid - 1] : 0;
    st[tid] = s;
    invlen[tid] = 1.0f / (float)(en[tid] - s);
  }
  __syncthreads();
  if (fc == 0 && tid < N_) {
    int g = tid;
    ig[(b * N_ + g) * 2 + 0] = (g < G) ? st[g] : 0;
    ig[(b * N_ + g) * 2 + 1] = (g < G) ? en[g] : 0;
  }

  // mean phase: 2 consecutive f per thread, 4 group-slots per pass
  const int f = fc * 128 + (tid & 63) * 2;
  const float* xb = x + (size_t)b * N_ * FIN_ + f;
  for (int g = tid >> 6; g < N_; g += 4) {
    u16 h0 = 0, h1 = 0, l0 = 0, l1 = 0;
    if (g < G) {
      int s = st[g], e = en[g];
      float s0 = 0.0f, s1 = 0.0f;
      for (int k = s; k < e; ++k) {
        float2 v = *(const float2*)(xb + (size_t)k * FIN_);
        s0 += v.x; s1 += v.y;
      }
      float il = invlen[g];
      float m0 = s0 * il, m1 = s1 * il;
      h0 = f2bf(m0); l0 = f2bf(m0 - b2f(h0));
      h1 = f2bf(m1); l1 = f2bf(m1 - b2f(h1));
    }
    size_t oo = ((size_t)b * N_ + g) * FIN_ + f;
    u16x2 hv = {h0, h1}, lv = {l0, l1};
    *(u16x2*)(xoh + oo) = hv;
    *(u16x2*)(xol + oo) = lv;
  }
}

// ---------------------------------------------------------------------------
// Weight pack kernels: LDS-tiled transpose (32x32, +1 pad) -> coalesced
// reads AND writes.
// ---------------------------------------------------------------------------
__global__ __launch_bounds__(256) void pack_wgT(  // Wg_w[768][1024] -> WgT[1024][768]
    const float* __restrict__ w, u16* __restrict__ th, u16* __restrict__ tl)
{
  __shared__ float t[32][33];
  const int k0 = blockIdx.x * 32, n0 = blockIdx.y * 32;
  const int r = threadIdx.x >> 3;
  const int c = (threadIdx.x & 7) * 4;
  float4 v = *(const float4*)(w + (size_t)(k0 + r) * 1024 + n0 + c);
  t[r][c] = v.x; t[r][c + 1] = v.y; t[r][c + 2] = v.z; t[r][c + 3] = v.w;
  __syncthreads();
  u16x4 hv, lv;
#pragma unroll
  for (int i = 0; i < 4; ++i) {
    float xv = t[c + i][r];
    u16 h = f2bf(xv);
    hv[i] = h; lv[i] = f2bf(xv - b2f(h));
  }
  size_t dst = (size_t)(n0 + r) * 768 + k0 + c;
  *(u16x4*)(th + dst) = hv;
  *(u16x4*)(tl + dst) = lv;
}
__global__ __launch_bounds__(256) void pack_hwT(  // hW_w[8][1024][512] -> hWT[4096][1024]
    const float* __restrict__ w, u16* __restrict__ th, u16* __restrict__ tl)
{
  __shared__ float t[32][33];
  const int o0 = blockIdx.x * 32, f0 = blockIdx.y * 32, hd = blockIdx.z;
  const int r = threadIdx.x >> 3;
  const int c = (threadIdx.x & 7) * 4;
  float4 v = *(const float4*)(w + ((size_t)hd * 1024 + f0 + r) * 512 + o0 + c);
  t[r][c] = v.x; t[r][c + 1] = v.y; t[r][c + 2] = v.z; t[r][c + 3] = v.w;
  __syncthreads();
  u16x4 hv, lv;
#pragma unroll
  for (int i = 0; i < 4; ++i) {
    float xv = t[c + i][r];
    u16 h = f2bf(xv);
    hv[i] = h; lv[i] = f2bf(xv - b2f(h));
  }
  size_t dst = ((size_t)hd * 512 + o0 + r) * 1024 + f0 + c;
  *(u16x4*)(th + dst) = hv;
  *(u16x4*)(tl + dst) = lv;
}
__global__ __launch_bounds__(256) void pack_owT(  // oW_w[4096][512] -> oWT[512][4096]
    const float* __restrict__ w, u16* __restrict__ th, u16* __restrict__ tl)
{
  __shared__ float t[32][33];
  const int k0 = blockIdx.x * 32, o0 = blockIdx.y * 32;
  const int r = threadIdx.x >> 3;
  const int c = (threadIdx.x & 7) * 4;
  float4 v = *(const float4*)(w + (size_t)(k0 + r) * 512 + o0 + c);
  t[r][c] = v.x; t[r][c + 1] = v.y; t[r][c + 2] = v.z; t[r][c + 3] = v.w;
  __syncthreads();
  u16x4 hv, lv;
#pragma unroll
  for (int i = 0; i < 4; ++i) {
    float xv = t[c + i][r];
    u16 h = f2bf(xv);
    hv[i] = h; lv[i] = f2bf(xv - b2f(h));
  }
  size_t dst = (size_t)(o0 + r) * 4096 + k0 + c;
  *(u16x4*)(th + dst) = hv;
  *(u16x4*)(tl + dst) = lv;
}

// ---------------------------------------------------------------------------
// OLD split-bf16 MFMA GEMM (128x128, reg-prefetch 2-phase). Kept for the
// small-tile launches (x1T per-z, G7 split-K).
// ---------------------------------------------------------------------------
__global__ __launch_bounds__(256) void mfma_split_gemm(
    const u16* __restrict__ Ah, const u16* __restrict__ Al,
    const u16* __restrict__ Bh, const u16* __restrict__ Bl,
    const float* __restrict__ bias, int bias_mode,   // 0 none, 1 per-n, 2 per-m
    u16* __restrict__ Oh, u16* __restrict__ Ol, float* __restrict__ Of,
    int out_f32, int do_elu,
    int K, int lda, int ldb,
    long long Az, long long Bz,
    int msh, long long s_mb, int nsh, long long s_nb, long long s_n,
    long long zb_s, long long zh_s, int zH)
{
  __shared__ u16 As_h[128][40];
  __shared__ u16 As_l[128][40];
  __shared__ u16 Bs_h[128][40];
  __shared__ u16 Bs_l[128][40];
  const int tid = threadIdx.x;
  const int wave = tid >> 6, lane = tid & 63;
  const int wm = (wave >> 1) * 64, wn = (wave & 1) * 64;
  const int bn = blockIdx.x * 128, bm = blockIdx.y * 128;
  const int z = blockIdx.z;
  const u16* Ahb = Ah + (long long)z * Az;
  const u16* Alb = Al + (long long)z * Az;
  const u16* Bhb = Bh + (long long)z * Bz;
  const u16* Blb = Bl + (long long)z * Bz;
  const int lm = lane & 15, lq = lane >> 4;

  const int sr = tid >> 1;
  const int sc = (tid & 1) * 16;
  const size_t ga = (size_t)(bm + sr) * lda + sc;
  const size_t gb = (size_t)(bn + sr) * ldb + sc;

  f32x4 acc[4][4];
#pragma unroll
  for (int i = 0; i < 4; ++i)
#pragma unroll
    for (int j = 0; j < 4; ++j) acc[i][j] = (f32x4){0.0f, 0.0f, 0.0f, 0.0f};

  uint4 r0, r1, r2, r3, r4, r5, r6, r7;
  r0 = *(const uint4*)(Ahb + ga);
  r1 = *(const uint4*)(Ahb + ga + 8);
  r2 = *(const uint4*)(Alb + ga);
  r3 = *(const uint4*)(Alb + ga + 8);
  r4 = *(const uint4*)(Bhb + gb);
  r5 = *(const uint4*)(Bhb + gb + 8);
  r6 = *(const uint4*)(Blb + gb);
  r7 = *(const uint4*)(Blb + gb + 8);

  for (int k0 = 0; k0 < K; k0 += 32) {
    __syncthreads();
    *(uint4*)&As_h[sr][sc] = r0;
    *(uint4*)&As_h[sr][sc + 8] = r1;
    *(uint4*)&As_l[sr][sc] = r2;
    *(uint4*)&As_l[sr][sc + 8] = r3;
    *(uint4*)&Bs_h[sr][sc] = r4;
    *(uint4*)&Bs_h[sr][sc + 8] = r5;
    *(uint4*)&Bs_l[sr][sc] = r6;
    *(uint4*)&Bs_l[sr][sc + 8] = r7;
    __syncthreads();
    int kn = k0 + 32;
    if (kn < K) {
      r0 = *(const uint4*)(Ahb + ga + kn);
      r1 = *(const uint4*)(Ahb + ga + kn + 8);
      r2 = *(const uint4*)(Alb + ga + kn);
      r3 = *(const uint4*)(Alb + ga + kn + 8);
      r4 = *(const uint4*)(Bhb + gb + kn);
      r5 = *(const uint4*)(Bhb + gb + kn + 8);
      r6 = *(const uint4*)(Blb + gb + kn);
      r7 = *(const uint4*)(Blb + gb + kn + 8);
    }
    s16x8 fa_h[4], fa_l[4], fb_h[4], fb_l[4];
#pragma unroll
    for (int t = 0; t < 4; ++t) {
      fa_h[t] = *(const s16x8*)&As_h[wm + t * 16 + lm][lq * 8];
      fa_l[t] = *(const s16x8*)&As_l[wm + t * 16 + lm][lq * 8];
      fb_h[t] = *(const s16x8*)&Bs_h[wn + t * 16 + lm][lq * 8];
      fb_l[t] = *(const s16x8*)&Bs_l[wn + t * 16 + lm][lq * 8];
    }
#pragma unroll
    for (int i = 0; i < 4; ++i)
#pragma unroll
      for (int j = 0; j < 4; ++j) {
        acc[i][j] = __builtin_amdgcn_mfma_f32_16x16x32_bf16(fa_h[i], fb_h[j], acc[i][j], 0, 0, 0);
        acc[i][j] = __builtin_amdgcn_mfma_f32_16x16x32_bf16(fa_h[i], fb_l[j], acc[i][j], 0, 0, 0);
        acc[i][j] = __builtin_amdgcn_mfma_f32_16x16x32_bf16(fa_l[i], fb_h[j], acc[i][j], 0, 0, 0);
      }
  }

  // ---- LDS-transpose epilogue ----
  __syncthreads();
  const long long zoff = (long long)(z / zH) * zb_s + (long long)(z % zH) * zh_s;
  const int mmask = (1 << msh) - 1;
  const int nmask = (1 << nsh) - 1;
  char* lds_raw = (char*)&As_h[0][0] + wave * 4608;
  const int rn = lane >> 2;
  const int rm = (lane & 3) * 16;

  if (out_f32) {
    float* slab = (float*)lds_raw;      // [16][68]
#pragma unroll
    for (int j = 0; j < 4; ++j) {
#pragma unroll
      for (int i = 0; i < 4; ++i) {
        int mb = bm + wm + i * 16 + lq * 4;
        int n = bn + wn + j * 16 + lm;
        f32x4 v = acc[i][j];
        if (bias_mode == 1) v += bias[n];
        else if (bias_mode == 2) { f32x4 b4 = *(const f32x4*)&bias[mb]; v += b4; }
        if (do_elu) {
          v.x = v.x > 0.0f ? v.x : expm1f(v.x);
          v.y = v.y > 0.0f ? v.y : expm1f(v.y);
          v.z = v.z > 0.0f ? v.z : expm1f(v.z);
          v.w = v.w > 0.0f ? v.w : expm1f(v.w);
        }
        *(f32x4*)&slab[lm * 68 + i * 16 + lq * 4] = v;
      }
      __syncthreads();
      int n = bn + wn + j * 16 + rn;
      int mbase = bm + wm + rm;
      long long off = (long long)(mbase >> msh) * s_mb + (mbase & mmask)
                    + (long long)(n >> nsh) * s_nb + (long long)(n & nmask) * s_n + zoff;
      const float* src = &slab[rn * 68 + rm];
      f32x4 v0 = *(const f32x4*)(src + 0);
      f32x4 v1 = *(const f32x4*)(src + 4);
      f32x4 v2 = *(const f32x4*)(src + 8);
      f32x4 v3 = *(const f32x4*)(src + 12);
      *(f32x4*)(Of + off + 0)  = v0;
      *(f32x4*)(Of + off + 4)  = v1;
      *(f32x4*)(Of + off + 8)  = v2;
      *(f32x4*)(Of + off + 12) = v3;
      __syncthreads();
    }
  } else {
    u16* slab_h = (u16*)lds_raw;        // [16][72]
    u16* slab_l = slab_h + 16 * 72;
#pragma unroll
    for (int j = 0; j < 4; ++j) {
#pragma unroll
      for (int i = 0; i < 4; ++i) {
        int mb = bm + wm + i * 16 + lq * 4;
        int n = bn + wn + j * 16 + lm;
        f32x4 v = acc[i][j];
        if (bias_mode == 1) v += bias[n];
        else if (bias_mode == 2) { f32x4 b4 = *(const f32x4*)&bias[mb]; v += b4; }
        if (do_elu) {
          v.x = v.x > 0.0f ? v.x : expm1f(v.x);
          v.y = v.y > 0.0f ? v.y : expm1f(v.y);
          v.z = v.z > 0.0f ? v.z : expm1f(v.z);
          v.w = v.w > 0.0f ? v.w : expm1f(v.w);
        }
        u16 h0 = f2bf(v.x), h1 = f2bf(v.y), h2 = f2bf(v.z), h3 = f2bf(v.w);
        u16x4 hv = {h0, h1, h2, h3};
        u16x4 lv = {f2bf(v.x - b2f(h0)), f2bf(v.y - b2f(h1)),
                    f2bf(v.z - b2f(h2)), f2bf(v.w - b2f(h3))};
        *(u16x4*)&slab_h[lm * 72 + i * 16 + lq * 4] = hv;
        *(u16x4*)&slab_l[lm * 72 + i * 16 + lq * 4] = lv;
      }
      __syncthreads();
      int n = bn + wn + j * 16 + rn;
      int mbase = bm + wm + rm;
      long long off = (long long)(mbase >> msh) * s_mb + (mbase & mmask)
                    + (long long)(n >> nsh) * s_nb + (long long)(n & nmask) * s_n + zoff;
      const u16* sh = &slab_h[rn * 72 + rm];
      const u16* sl = &slab_l[rn * 72 + rm];
      uint4 h0 = *(const uint4*)(sh + 0);
      uint4 h1 = *(const uint4*)(sh + 8);
      uint4 l0 = *(const uint4*)(sl + 0);
      uint4 l1 = *(const uint4*)(sl + 8);
      *(uint4*)(Oh + off + 0) = h0;
      *(uint4*)(Oh + off + 8) = h1;
      *(uint4*)(Ol + off + 0) = l0;
      *(uint4*)(Ol + off + 8) = l1;
      __syncthreads();
    }
  }
}

// ---------------------------------------------------------------------------
// Flat counted-vmcnt split-bf16 GEMM (R2-verified). BM=128, BN=256, BK=32,
// 8 waves (2Mx4N, 64x64 per wave). 3-deep LDS buffers staged by
// global_load_lds width=16 with pre-swizzled global source; hi|lo interleaved
// into 128B LDS rows with slot' = slot ^ (row&7) XOR swizzle.
// ONE vmcnt(6) + raw s_barrier + sched_barrier(0) per K-tile; loads stay in
// flight across the barrier (vmcnt never 0 in steady state).
// ---------------------------------------------------------------------------
#define G8_BUF 49152   // 16KB A + 32KB B per buffer, 3 buffers

#define STAGE_A8(T) do { const int _t = (T); if (_t < nt) {                    \
    const int _q = _t % 3;                                                     \
    _Pragma("unroll")                                                          \
    for (int rg_ = 0; rg_ < 2; ++rg_)                                          \
      __builtin_amdgcn_global_load_lds(                                        \
          (const __attribute__((address_space(1))) void*)(gA +                 \
              (size_t)_t * 32 + (size_t)rg_ * 8 * lda),                        \
          (__attribute__((address_space(3))) void*)(ldsAd + _q * G8_BUF +      \
              rg_ * 1024),                                                     \
          16, 0, 0);                                                           \
  } } while (0)

#define STAGE_B8(T) do { const int _t = (T); if (_t < nt) {                    \
    const int _q = _t % 3;                                                     \
    _Pragma("unroll")                                                          \
    for (int rg_ = 0; rg_ < 4; ++rg_)                                          \
      __builtin_amdgcn_global_load_lds(                                        \
          (const __attribute__((address_space(1))) void*)(gB +                 \
              (size_t)_t * 32 + (size_t)rg_ * 8 * ldb),                        \
          (__attribute__((address_space(3))) void*)(ldsBd + _q * G8_BUF +      \
              rg_ * 1024),                                                     \
          16, 0, 0);                                                           \
  } } while (0)

__global__ __launch_bounds__(512, 2) void mfma_split_gemm8(
    const u16* __restrict__ Ah, const u16* __restrict__ Al,
    const u16* __restrict__ Bh, const u16* __restrict__ Bl,
    const float* __restrict__ bias, int bias_mode,   // 1 per-n, 2 per-m
    u16* __restrict__ Oh, u16* __restrict__ Ol,
    int K, int lda, int ldb,
    int msh, long long s_mb, int nsh, long long s_nb, long long s_n)
{
  __shared__ __align__(128) char ldsb[3 * G8_BUF];   // 144 KB
  const int tid = threadIdx.x;
  const int wave = tid >> 6, lane = tid & 63;
  const int wm = (wave >> 2) * 64, wn = (wave & 3) * 64;
  const int bn = blockIdx.x * 256, bm = blockIdx.y * 128;
  const int lm = lane & 15, lq = lane >> 4;
  const int nt = K >> 5;

  // staging geometry: lane -> (row srow, phys slot); logical slot = phys ^ row
  const int srow = lane >> 3;
  const int sl = (lane & 7) ^ srow;          // logical slot this lane feeds
  const int scol = (sl & 3) * 8;             // k-offset (u16) within tile
  const u16* Asel = (sl < 4) ? Ah : Al;
  const u16* Bsel = (sl < 4) ? Bh : Bl;

  // hoisted per-wave staging bases
  const u16* gA = Asel + (size_t)(bm + wave * 16 + srow) * lda + scol;
  const u16* gB = Bsel + (size_t)(bn + wave * 32 + srow) * ldb + scol;
  char* ldsAd = ldsb + wave * 2048;            // A rows wave*16.., lane*16 added by HW
  char* ldsBd = ldsb + 16384 + wave * 4096;    // B rows wave*32..

  // read geometry: frag row r has r&7 == lm&7; hi slot lq -> phys lq^(lm&7)
  const int hbyt = (lq ^ (lm & 7)) * 16;
  const int lbyt = hbyt ^ 64;

  f32x4 acc[4][4];
#pragma unroll
  for (int i = 0; i < 4; ++i)
#pragma unroll
    for (int j = 0; j < 4; ++j) acc[i][j] = (f32x4){0.0f, 0.0f, 0.0f, 0.0f};

  // prologue: stage tiles 0 and 1 (FIFO: tile0's 6 loads first)
  STAGE_A8(0); STAGE_B8(0);
  STAGE_A8(1); STAGE_B8(1);
  if (nt > 1) asm volatile("s_waitcnt vmcnt(6)" ::: "memory");
  else        asm volatile("s_waitcnt vmcnt(0)" ::: "memory");
  __builtin_amdgcn_s_barrier();
  __builtin_amdgcn_sched_barrier(0);

#pragma unroll 3
  for (int t = 0; t < nt; ++t) {
    const int q = t % 3;
    // issue next-next tile's staging first (latency hiding)
    STAGE_A8(t + 2);
    STAGE_B8(t + 2);
    const char* Abase = ldsb + q * G8_BUF + (wm + lm) * 128;
    const char* Bbase = ldsb + q * G8_BUF + 16384 + (wn + lm) * 128;
    s16x8 fa[4][2], fb[4][2];
#pragma unroll
    for (int i = 0; i < 4; ++i) {
      fb[i][0] = *(const s16x8*)(Bbase + i * 2048 + hbyt);
      fb[i][1] = *(const s16x8*)(Bbase + i * 2048 + lbyt);
      fa[i][0] = *(const s16x8*)(Abase + i * 2048 + hbyt);
      fa[i][1] = *(const s16x8*)(Abase + i * 2048 + lbyt);
    }
    __builtin_amdgcn_s_setprio(1);
#pragma unroll
    for (int i = 0; i < 4; ++i)
#pragma unroll
      for (int j = 0; j < 4; ++j) {
        acc[i][j] = __builtin_amdgcn_mfma_f32_16x16x32_bf16(fa[i][0], fb[j][0], acc[i][j], 0, 0, 0);
        acc[i][j] = __builtin_amdgcn_mfma_f32_16x16x32_bf16(fa[i][0], fb[j][1], acc[i][j], 0, 0, 0);
        acc[i][j] = __builtin_amdgcn_mfma_f32_16x16x32_bf16(fa[i][1], fb[j][0], acc[i][j], 0, 0, 0);
      }
    __builtin_amdgcn_s_setprio(0);
    if (t + 1 < nt) {
      if (t + 2 < nt) asm volatile("s_waitcnt vmcnt(6)" ::: "memory");
      else            asm volatile("s_waitcnt vmcnt(0)" ::: "memory");
      __builtin_amdgcn_s_barrier();
      __builtin_amdgcn_sched_barrier(0);
    }
  }

  // ---- LDS-transpose epilogue (split bf16 hi/lo out) ----
  __syncthreads();
  const int mmask = (1 << msh) - 1;
  const int nmask = (1 << nsh) - 1;
  char* lds_raw = ldsb + wave * 4608;
  const int rn = lane >> 2;
  const int rm = (lane & 3) * 16;
  u16* slab_h = (u16*)lds_raw;        // [16][72]
  u16* slab_l = slab_h + 16 * 72;
#pragma unroll
  for (int j = 0; j < 4; ++j) {
#pragma unroll
    for (int i = 0; i < 4; ++i) {
      int mb = bm + wm + i * 16 + lq * 4;
      int n = bn + wn + j * 16 + lm;
      f32x4 v = acc[i][j];
      if (bias_mode == 1) v += bias[n];
      else if (bias_mode == 2) { f32x4 b4 = *(const f32x4*)&bias[mb]; v += b4; }
      u16 h0 = f2bf(v.x), h1 = f2bf(v.y), h2 = f2bf(v.z), h3 = f2bf(v.w);
      u16x4 hv = {h0, h1, h2, h3};
      u16x4 lv = {f2bf(v.x - b2f(h0)), f2bf(v.y - b2f(h1)),
                  f2bf(v.z - b2f(h2)), f2bf(v.w - b2f(h3))};
      *(u16x4*)&slab_h[lm * 72 + i * 16 + lq * 4] = hv;
      *(u16x4*)&slab_l[lm * 72 + i * 16 + lq * 4] = lv;
    }
    __syncthreads();
    int n = bn + wn + j * 16 + rn;
    int mbase = bm + wm + rm;
    long long off = (long long)(mbase >> msh) * s_mb + (mbase & mmask)
                  + (long long)(n >> nsh) * s_nb + (long long)(n & nmask) * s_n;
    const u16* sh = &slab_h[rn * 72 + rm];
    const u16* slp = &slab_l[rn * 72 + rm];
    uint4 h0 = *(const uint4*)(sh + 0);
    uint4 h1 = *(const uint4*)(sh + 8);
    uint4 l0 = *(const uint4*)(slp + 0);
    uint4 l1 = *(const uint4*)(slp + 8);
    *(uint4*)(Oh + off + 0) = h0;
    *(uint4*)(Oh + off + 8) = h1;
    *(uint4*)(Ol + off + 0) = l0;
    *(uint4*)(Ol + off + 8) = l1;
    __syncthreads();
  }
}

// ---------------------------------------------------------------------------
// Split-K reduce for G7.
// ---------------------------------------------------------------------------
__global__ __launch_bounds__(256) void reduce4_bias(
    const float* __restrict__ ps, const float* __restrict__ bias,
    float* __restrict__ h2T, int col0)
{
  int base = (blockIdx.x * 256 + threadIdx.x) * 4;   // 512*2048 elements
  int o = base >> 11, m = base & 2047;
  f32x4 v = *(const f32x4*)(ps + base);
  v += *(const f32x4*)(ps + base + 1048576);
  v += *(const f32x4*)(ps + base + 2097152);
  v += *(const f32x4*)(ps + base + 3145728);
  v += bias[o];
  *(f32x4*)(h2T + (size_t)o * 8192 + col0 + m) = v;
}

// ---------------------------------------------------------------------------
// esrc/edst from hT (split bf16): block per (bc,head), 512 threads.
// ---------------------------------------------------------------------------
__global__ __launch_bounds__(512) void dot_pairs_hT(
    const u16* __restrict__ hTh, const u16* __restrict__ hTl,
    const float* __restrict__ W,   // ha_w [8][1024]
    float* __restrict__ esrc, float* __restrict__ edst)
{
  int bh = blockIdx.x;
  int head = bh & 7;
  int tid = threadIdx.x;
  int os = tid >> 7, i = tid & 127;
  const u16* ph = hTh + (size_t)bh * 65536 + (size_t)os * 16384 + i;
  const u16* pl = hTl + (size_t)bh * 65536 + (size_t)os * 16384 + i;
  const float* w1 = W + head * 1024 + os * 128;
  float s1 = 0.0f, s2 = 0.0f;
#pragma unroll 8
  for (int o = 0; o < 128; ++o) {
    float hv = b2f(ph[o * 128]) + b2f(pl[o * 128]);
    s1 = fmaf(hv, w1[o], s1);
    s2 = fmaf(hv, w1[512 + o], s2);
  }
  __shared__ float sh1[4][128], sh2[4][128];
  sh1[os][i] = s1;
  sh2[os][i] = s2;
  __syncthreads();
  if (os == 0) {
    esrc[bh * 128 + i] = sh1[0][i] + sh1[1][i] + sh1[2][i] + sh1[3][i];
    edst[bh * 128 + i] = sh2[0][i] + sh2[1][i] + sh2[2][i] + sh2[3][i];
  }
}

// e2 dots from h2T (fp32): block per b, 512 threads.
__global__ __launch_bounds__(512) void dot_pairs_h2T(
    const float* __restrict__ h2T, const float* __restrict__ oa,
    float* __restrict__ e2s, float* __restrict__ e2d)
{
  int b = blockIdx.x;
  int tid = threadIdx.x;
  int os = tid >> 7, i = tid & 127;
  const float* hb = h2T + (size_t)os * 128 * 8192 + b * 128 + i;
  const float* oa1 = oa + os * 128;
  float s1 = 0.0f, s2 = 0.0f;
#pragma unroll 8
  for (int o = 0; o < 128; ++o) {
    float hv = hb[(size_t)o * 8192];
    s1 = fmaf(hv, oa1[o], s1);
    s2 = fmaf(hv, oa1[512 + o], s2);
  }
  __shared__ float sh1[4][128], sh2[4][128];
  sh1[os][i] = s1;
  sh2[os][i] = s2;
  __syncthreads();
  if (os == 0) {
    e2s[b * 128 + i] = sh1[0][i] + sh1[1][i] + sh1[2][i] + sh1[3][i];
    e2d[b * 128 + i] = sh2[0][i] + sh2[1][i] + sh2[2][i] + sh2[3][i];
  }
}

// ---------------------------------------------------------------------------
// Edge softmax; split=1 -> bf16 hi/lo output, else fp32.  adj pre-offset.
// ---------------------------------------------------------------------------
__global__ __launch_bounds__(64) void edge_softmax_kernel(
    const float* __restrict__ esrc, const float* __restrict__ edst,
    const float* __restrict__ bias, const float* __restrict__ adj,
    float* __restrict__ attf, u16* __restrict__ atth, u16* __restrict__ attl,
    int H, int split)
{
  int row = blockIdx.x;
  int lane = threadIdx.x;
  int i = row & 127;
  int bh = row >> 7;
  int hd = bh % H;
  int b = bh / H;
  float es = esrc[row] + bias[hd];
  const float* adjr = adj + ((size_t)b * N_ + i) * N_;
  const float* edr = edst + (size_t)bh * N_;
  float v[2];
#pragma unroll
  for (int t = 0; t < 2; ++t) {
    int j = lane + t * 64;
    float e = es + edr[j];
    e = (e >= 0.0f) ? e : 0.2f * e;
    v[t] = (adjr[j] > 0.0f) ? e : NEG_E_;
  }
  float mx = fmaxf(v[0], v[1]);
  for (int off = 32; off; off >>= 1) mx = fmaxf(mx, __shfl_xor(mx, off));
  float e0 = expf(v[0] - mx), e1 = expf(v[1] - mx);
  float sm = e0 + e1;
  for (int off = 32; off; off >>= 1) sm += __shfl_xor(sm, off);
  float inv = 1.0f / sm;
  float p0 = e0 * inv, p1 = e1 * inv;
  size_t base = (size_t)row * N_;
  if (split) {
    u16 h0 = f2bf(p0), h1 = f2bf(p1);
    atth[base + lane] = h0;
    attl[base + lane] = f2bf(p0 - b2f(h0));
    atth[base + lane + 64] = h1;
    attl[base + lane + 64] = f2bf(p1 - b2f(h1));
  } else {
    attf[base + lane] = p0;
    attf[base + lane + 64] = p1;
  }
}

// ---------------------------------------------------------------------------
// Stage-2 fp32 batched GEMM + ELU (h2T[512][8192] B-layout).
// ---------------------------------------------------------------------------
__global__ __launch_bounds__(256) void bgemm_elu_bt_f32(
    const float* __restrict__ A, const float* __restrict__ BT,
    float* __restrict__ C)
{
  __shared__ float As[16][64];
  __shared__ float Bs[16][68];
  const int tid = threadIdx.x;
  const int tm = blockIdx.x >> 3, tn = blockIdx.x & 7;
  const int bm = tm * 64, bn = tn * 64;
  const int b = blockIdx.y;
  const float* Ab = A + (size_t)b * 16384;
  const float* BTb = BT + (size_t)b * 128;
  const int ty = tid >> 4, tx = tid & 15;
  const int ar = tid >> 2, ac = (tid & 3) * 4;
  float acc[4][4];
#pragma unroll
  for (int i = 0; i < 4; ++i)
#pragma unroll
    for (int j = 0; j < 4; ++j) acc[i][j] = 0.0f;

  for (int k0 = 0; k0 < 128; k0 += 16) {
    float4 av = *(const float4*)(Ab + (size_t)(bm + ar) * 128 + k0 + ac);
    float4 bv = *(const float4*)(BTb + (size_t)(bn + ar) * 8192 + k0 + ac);
    __syncthreads();
    As[ac + 0][ar] = av.x; As[ac + 1][ar] = av.y; As[ac + 2][ar] = av.z; As[ac + 3][ar] = av.w;
    Bs[ac + 0][ar] = bv.x; Bs[ac + 1][ar] = bv.y; Bs[ac + 2][ar] = bv.z; Bs[ac + 3][ar] = bv.w;
    __syncthreads();
#pragma unroll
    for (int kk = 0; kk < 16; ++kk) {
      float a[4], bb[4];
      *(float4*)a  = *(const float4*)&As[kk][ty * 4];
      *(float4*)bb = *(const float4*)&Bs[kk][tx * 4];
#pragma unroll
      for (int i = 0; i < 4; ++i)
#pragma unroll
        for (int j = 0; j < 4; ++j)
          acc[i][j] = fmaf(a[i], bb[j], acc[i][j]);
    }
  }
#pragma unroll
  for (int i = 0; i < 4; ++i) {
    int row = b * 128 + bm + ty * 4 + i;
    float4 v;
    v.x = acc[i][0] > 0.0f ? acc[i][0] : expm1f(acc[i][0]);
    v.y = acc[i][1] > 0.0f ? acc[i][1] : expm1f(acc[i][1]);
    v.z = acc[i][2] > 0.0f ? acc[i][2] : expm1f(acc[i][2]);
    v.w = acc[i][3] > 0.0f ? acc[i][3] : expm1f(acc[i][3]);
    *(float4*)(C + (size_t)row * 512 + bn + tx * 4) = v;
  }
}

// ---------------------------------------------------------------------------
// logits = x2 @ fin_w + fin_b  (one wave per row)
// ---------------------------------------------------------------------------
__global__ __launch_bounds__(256) void logits_kernel(
    const float* __restrict__ X, const float* __restrict__ w,
    const float* __restrict__ bptr, float* __restrict__ out, int R)
{
  int wv = (blockIdx.x * 256 + threadIdx.x) >> 6;
  int lane = threadIdx.x & 63;
  if (wv >= R) return;
  const float* xr = X + (size_t)wv * 512;
  float s = 0.0f;
#pragma unroll
  for (int i = 0; i < 8; ++i) {
    int c = lane + i * 64;
    s = fmaf(xr[c], w[c], s);
  }
  for (int off = 32; off; off >>= 1) s += __shfl_down(s, off);
  if (lane == 0) out[wv] = s + bptr[0];
}

// ---------------------------------------------------------------------------
// Final: scores -> stable rank -> gather fix -> expand.
// ---------------------------------------------------------------------------
__global__ __launch_bounds__(128) void finalize_kernel(
    const float* __restrict__ logits, const float* __restrict__ tag,
    const float* __restrict__ amask, const int* __restrict__ ig,
    int* __restrict__ out)
{
  const int b = blockIdx.x, tid = threadIdx.x;
  __shared__ float red[N_];
  __shared__ float scs[N_];
  __shared__ int fs[N_], fe[N_], lens[N_], csum[N_];
  __shared__ int redi[N_];

  float lg = logits[b * N_ + tid];
  float tg = tag[b * N_ + tid];
  float am = amask[b * N_ + tid];
  float m = (tg > 0.0f) ? am : 0.0f;

  float in1 = (m > 0.0f) ? lg * m : NEG_S_;
  red[tid] = in1; __syncthreads();
  for (int s = 64; s > 0; s >>= 1) { if (tid < s) red[tid] = fmaxf(red[tid], red[tid + s]); __syncthreads(); }
  float M1 = red[0]; __syncthreads();
  float e1 = expf(in1 - M1);
  red[tid] = e1; __syncthreads();
  for (int s = 64; s > 0; s >>= 1) { if (tid < s) red[tid] += red[tid + s]; __syncthreads(); }
  float S1 = red[0]; __syncthreads();
  float sc = e1 / S1;

  red[tid] = m; __syncthreads();
  for (int s = 64; s > 0; s >>= 1) { if (tid < s) red[tid] += red[tid + s]; __syncthreads(); }
  float SM = red[0]; __syncthreads();

  float in2 = (m > 0.0f) ? ((float)(N_ - tid) / SM) * m : NEG_S_;
  red[tid] = in2; __syncthreads();
  for (int s = 64; s > 0; s >>= 1) { if (tid < s) red[tid] = fmaxf(red[tid], red[tid + s]); __syncthreads(); }
  float M2 = red[0]; __syncthreads();
  float e2 = expf(in2 - M2);
  red[tid] = e2; __syncthreads();
  for (int s = 64; s > 0; s >>= 1) { if (tid < s) red[tid] += red[tid + s]; __syncthreads(); }
  float S2 = red[0]; __syncthreads();
  float ii = e2 / S2;

  scs[tid] = sc + ii;
  __syncthreads();

  float si = scs[tid];
  int rank = 0;
  for (int j = 0; j < N_; ++j) {
    float sj = scs[j];
    rank += (sj > si) || (sj == si && j < tid);
  }
  fs[tid] = ig[(b * N_ + rank) * 2 + 0];
  fe[tid] = ig[(b * N_ + rank) * 2 + 1];
  __syncthreads();

  redi[tid] = (fs[tid] == 0 && fe[tid] == 0) ? tid : N_;
  __syncthreads();
  for (int s = 64; s > 0; s >>= 1) { if (tid < s) redi[tid] = min(redi[tid], redi[tid + s]); __syncthreads(); }
  int fz = redi[0]; __syncthreads();
  lens[tid] = (tid < fz) ? (fe[tid] - fs[tid]) : 0;
  __syncthreads();
  if (tid == 0) {
    int r = 0;
    for (int k = 0; k < N_; ++k) { r += lens[k]; csum[k] = r; }
  }
  __syncthreads();
  int total = csum[N_ - 1];
  int l = tid;
  int k = 0;
  while (k < N_ && csum[k] <= l) ++k;
  if (k > N_ - 1) k = N_ - 1;
  int val = fs[k] + (l - (csum[k] - lens[k]));
  out[b * N_ + l] = (l < total) ? val : l;
}

// ---------------------------------------------------------------------------
extern "C" void kernel_launch(void* const* d_in, const int* in_sizes, int n_in,
                              void* d_out, int out_size, void* d_ws, size_t ws_size,
                              hipStream_t stream)
{
  const float* x     = (const float*)d_in[0];
  const float* tag   = (const float*)d_in[1];
  const int*   offs  = (const int*)  d_in[2];
  const float* amask = (const float*)d_in[3];
  const float* adj   = (const float*)d_in[4];
  const float* Wg_w  = (const float*)d_in[5];
  const float* Wg_b  = (const float*)d_in[6];
  const float* hW_w  = (const float*)d_in[7];
  const float* hW_b  = (const float*)d_in[8];
  const float* ha_w  = (const float*)d_in[9];
  const float* ha_b  = (const float*)d_in[10];
  const float* oW_w  = (const float*)d_in[11];
  const float* oW_b  = (const float*)d_in[12];
  const float* oa_w  = (const float*)d_in[13];
  const float* oa_b  = (const float*)d_in[14];
  const float* fin_w = (const float*)d_in[15];
  const float* fin_b = (const float*)d_in[16];
  int* out = (int*)d_out;

  // ---- workspace: 154.5 MB (< proven-safe 197.5 MB) ----
  char* ws = (char*)d_ws;
  size_t o = 0;
  int* ig     = (int*)(ws + o);  o += 131072;
  u16* WgT_h  = (u16*)(ws + o);  o += 1572864;
  u16* WgT_l  = (u16*)(ws + o);  o += 1572864;
  u16* hWT_h  = (u16*)(ws + o);  o += 8388608;
  u16* hWT_l  = (u16*)(ws + o);  o += 8388608;
  u16* oWT_h  = (u16*)(ws + o);  o += 4194304;
  u16* oWT_l  = (u16*)(ws + o);  o += 4194304;
  float* h2T  = (float*)(ws + o); o += 16777216;
  float* esrc = (float*)(ws + o); o += 65536;
  float* edst = (float*)(ws + o); o += 65536;
  float* e2s  = (float*)(ws + o); o += 32768;
  float* e2d  = (float*)(ws + o); o += 32768;
  float* lgts = (float*)(ws + o); o += 32768;
  u16* xw_h   = (u16*)(ws + o);  o += 16777216;   // full-batch xw (8192x1024)
  u16* xw_l   = (u16*)(ws + o);  o += 16777216;
  char* pool  = ws + o;          o += 75497472;   // overlaid region

  // pool overlays (time-sliced):
  u16* xoff_h = (u16*)(pool + 0);          // full-batch x_off (8192x768), dead after G2
  u16* xoff_l = (u16*)(pool + 12582912);
  u16* hT_h   = (u16*)(pool + 0);          // per-chunk hT (dead after x1T)
  u16* hT_l   = (u16*)(pool + 16777216);
  u16* x1_h   = (u16*)(pool + 33554432);   // per-chunk x1
  u16* x1_l   = (u16*)(pool + 50331648);
  u16* att_h  = (u16*)(pool + 67108864);   // per-chunk att
  u16* att_l  = (u16*)(pool + 71303168);
  float* ps   = (float*)(pool + 0);        // G7 split-K partials (overlays dead hT)
  float* att2 = (float*)(pool + 0);        // stage-2 tail
  float* x2   = (float*)(pool + 4194304);

  // weight packing (LDS-tiled transpose, coalesced both sides)
  pack_wgT<<<dim3(24, 32), 256, 0, stream>>>(Wg_w, WgT_h, WgT_l);
  pack_hwT<<<dim3(16, 32, 8), 256, 0, stream>>>(hW_w, hWT_h, hWT_l);
  pack_owT<<<dim3(128, 16), 256, 0, stream>>>(oW_w, oWT_h, oWT_l);

  // full-batch group pool -> x_off (split), ig  (R3 parallel form)
  group_pool_kernel<<<dim3(B_, 6), 256, 0, stream>>>(x, offs, xoff_h, xoff_l, ig);

  // G2 full-batch (swapped): xw[node][feat] = x_off @ Wg + Wg_b.
  // M=1024(feat), N=8192(node), K=768.  Flat gemm8: grid 32x8 = 256.
  mfma_split_gemm8<<<dim3(32, 8), 512, 0, stream>>>(
      WgT_h, WgT_l, xoff_h, xoff_l, Wg_b, 2,
      xw_h, xw_l,
      768, 768, 768,
      10, 0, 13, 0, 1024);

  for (int b0 = 0; b0 < B_; b0 += CHUNK_) {
    // G3: hT[(bc*8+h)*512+o][i] = (xw @ hW + hW_b)^T. M=2048,N=4096,K=1024.
    // Flat gemm8: grid 16x16 = 256 blocks.
    mfma_split_gemm8<<<dim3(16, 16), 512, 0, stream>>>(
        xw_h + (size_t)b0 * 131072, xw_l + (size_t)b0 * 131072,
        hWT_h, hWT_l, hW_b, 1,
        hT_h, hT_l,
        1024, 1024, 1024,
        7, 524288, 9, 65536, 128);

    dot_pairs_hT<<<CHUNK_ * 8, 512, 0, stream>>>(hT_h, hT_l, ha_w, esrc, edst);
    edge_softmax_kernel<<<CHUNK_ * 8 * 128, 64, 0, stream>>>(
        esrc, edst, ha_b, adj + (size_t)b0 * 16384, nullptr, att_h, att_l, 8, 1);

    // x1T: per z=(bc,h): M=512(o),N=128(i),K=128(j)
    mfma_split_gemm<<<dim3(1, 4, CHUNK_ * 8), 256, 0, stream>>>(
        hT_h, hT_l, att_h, att_l, nullptr, 0,
        x1_h, x1_l, nullptr, 0, 1,
        128, 128, 128, 65536, 16384,
        9, 0, 7, 0, 4096, 524288, 512, 8);

    // G7 (split-K=4): M=2048,N=512,K=1024/slice  (ps overlays dead hT)
    mfma_split_gemm<<<dim3(4, 16, 4), 256, 0, stream>>>(
        x1_h, x1_l, oWT_h, oWT_l, nullptr, 0,
        nullptr, nullptr, ps, 1, 0,
        1024, 4096, 4096, 1024, 1024,
        13, 0, 9, 0, 2048, 0, 1048576, 4);
    reduce4_bias<<<1024, 256, 0, stream>>>(ps, oW_b, h2T, b0 * 128);
  }

  // attention-2 (fp32, unchunked)
  dot_pairs_h2T<<<64, 512, 0, stream>>>(h2T, oa_w, e2s, e2d);
  edge_softmax_kernel<<<8192, 64, 0, stream>>>(e2s, e2d, oa_b, adj,
      att2, nullptr, nullptr, 1, 0);
  bgemm_elu_bt_f32<<<dim3(16, 64), 256, 0, stream>>>(att2, h2T, x2);

  // logits + finalize
  logits_kernel<<<2048, 256, 0, stream>>>(x2, fin_w, fin_b, lgts, 8192);
  finalize_kernel<<<B_, 128, 0, stream>>>(lgts, tag, amask, ig, out);
}

// Round 4
// 775.594 us; speedup vs baseline: 1.1263x; 1.0342x over previous
//
#include <hip/hip_runtime.h>
#include <cstddef>
#include <cstdint>

#define B_ 64
#define N_ 128
#define FIN_ 768
#define NEG_E_ (-9.0e15f)
#define NEG_S_ (-9.0e10f)
#define CHUNK_ 16

typedef unsigned short u16;
typedef unsigned int u32;
typedef float f32x4 __attribute__((ext_vector_type(4)));
typedef short s16x8 __attribute__((ext_vector_type(8)));   // 8 bf16 frag
typedef u16 u16x4 __attribute__((ext_vector_type(4)));
typedef u16 u16x2 __attribute__((ext_vector_type(2)));

__device__ __forceinline__ u16 f2bf(float x) {
  u32 u = __float_as_uint(x);
  return (u16)((u + 0x7fffu + ((u >> 16) & 1u)) >> 16);
}
__device__ __forceinline__ float b2f(u16 h) {
  return __uint_as_float(((u32)h) << 16);
}

// ---------------------------------------------------------------------------
// Group pooling, R3 parallel form (verified).
// ---------------------------------------------------------------------------
__global__ __launch_bounds__(256) void group_pool_kernel(
    const float* __restrict__ x, const int* __restrict__ offs,
    u16* __restrict__ xoh, u16* __restrict__ xol, int* __restrict__ ig)
{
  const int b = blockIdx.x;
  const int fc = blockIdx.y;          // 6 chunks of 128 features
  const int tid = threadIdx.x;
  __shared__ int o0[N_ + 1], o1[N_];
  __shared__ int bi[N_], cs[N_];
  __shared__ int st[N_], en[N_];
  __shared__ float invlen[N_];
  __shared__ int fzs;

  if (tid < N_) {
    o0[tid] = offs[(b * N_ + tid) * 2 + 0];
    o1[tid] = offs[(b * N_ + tid) * 2 + 1];
  }
  if (tid == 0) { o0[N_] = 0; fzs = N_; }
  __syncthreads();
  if (tid < N_ && o0[tid] == 0 && o1[tid] == 0) atomicMin(&fzs, tid);
  __syncthreads();
  const int fz = fzs;
  if (tid < N_) {
    int nxt = o0[tid + 1];
    bi[tid] = (tid < fz && o1[tid] == nxt - 1) ? 1 : 0;
    cs[tid] = bi[tid];
  }
  __syncthreads();
  for (int d = 1; d < N_; d <<= 1) {
    int v = 0;
    if (tid < N_ && tid >= d) v = cs[tid - d];
    __syncthreads();
    if (tid < N_) cs[tid] += v;
    __syncthreads();
  }
  if (tid < N_ && bi[tid]) en[cs[tid] - 1] = tid + 1;
  __syncthreads();
  const int G = cs[N_ - 1];
  if (tid < G) {
    int s = tid ? en[tid - 1] : 0;
    st[tid] = s;
    invlen[tid] = 1.0f / (float)(en[tid] - s);
  }
  __syncthreads();
  if (fc == 0 && tid < N_) {
    int g = tid;
    ig[(b * N_ + g) * 2 + 0] = (g < G) ? st[g] : 0;
    ig[(b * N_ + g) * 2 + 1] = (g < G) ? en[g] : 0;
  }

  const int f = fc * 128 + (tid & 63) * 2;
  const float* xb = x + (size_t)b * N_ * FIN_ + f;
  for (int g = tid >> 6; g < N_; g += 4) {
    u16 h0 = 0, h1 = 0, l0 = 0, l1 = 0;
    if (g < G) {
      int s = st[g], e = en[g];
      float s0 = 0.0f, s1 = 0.0f;
      for (int k = s; k < e; ++k) {
        float2 v = *(const float2*)(xb + (size_t)k * FIN_);
        s0 += v.x; s1 += v.y;
      }
      float il = invlen[g];
      float m0 = s0 * il, m1 = s1 * il;
      h0 = f2bf(m0); l0 = f2bf(m0 - b2f(h0));
      h1 = f2bf(m1); l1 = f2bf(m1 - b2f(h1));
    }
    size_t oo = ((size_t)b * N_ + g) * FIN_ + f;
    u16x2 hv = {h0, h1}, lv = {l0, l1};
    *(u16x2*)(xoh + oo) = hv;
    *(u16x2*)(xol + oo) = lv;
  }
}

// ---------------------------------------------------------------------------
// Weight pack kernels (unchanged).
// ---------------------------------------------------------------------------
__global__ __launch_bounds__(256) void pack_wgT(  // Wg_w[768][1024] -> WgT[1024][768]
    const float* __restrict__ w, u16* __restrict__ th, u16* __restrict__ tl)
{
  __shared__ float t[32][33];
  const int k0 = blockIdx.x * 32, n0 = blockIdx.y * 32;
  const int r = threadIdx.x >> 3;
  const int c = (threadIdx.x & 7) * 4;
  float4 v = *(const float4*)(w + (size_t)(k0 + r) * 1024 + n0 + c);
  t[r][c] = v.x; t[r][c + 1] = v.y; t[r][c + 2] = v.z; t[r][c + 3] = v.w;
  __syncthreads();
  u16x4 hv, lv;
#pragma unroll
  for (int i = 0; i < 4; ++i) {
    float xv = t[c + i][r];
    u16 h = f2bf(xv);
    hv[i] = h; lv[i] = f2bf(xv - b2f(h));
  }
  size_t dst = (size_t)(n0 + r) * 768 + k0 + c;
  *(u16x4*)(th + dst) = hv;
  *(u16x4*)(tl + dst) = lv;
}
__global__ __launch_bounds__(256) void pack_hwT(  // hW_w[8][1024][512] -> hWT[4096][1024]
    const float* __restrict__ w, u16* __restrict__ th, u16* __restrict__ tl)
{
  __shared__ float t[32][33];
  const int o0 = blockIdx.x * 32, f0 = blockIdx.y * 32, hd = blockIdx.z;
  const int r = threadIdx.x >> 3;
  const int c = (threadIdx.x & 7) * 4;
  float4 v = *(const float4*)(w + ((size_t)hd * 1024 + f0 + r) * 512 + o0 + c);
  t[r][c] = v.x; t[r][c + 1] = v.y; t[r][c + 2] = v.z; t[r][c + 3] = v.w;
  __syncthreads();
  u16x4 hv, lv;
#pragma unroll
  for (int i = 0; i < 4; ++i) {
    float xv = t[c + i][r];
    u16 h = f2bf(xv);
    hv[i] = h; lv[i] = f2bf(xv - b2f(h));
  }
  size_t dst = ((size_t)hd * 512 + o0 + r) * 1024 + f0 + c;
  *(u16x4*)(th + dst) = hv;
  *(u16x4*)(tl + dst) = lv;
}
__global__ __launch_bounds__(256) void pack_owT(  // oW_w[4096][512] -> oWT[512][4096]
    const float* __restrict__ w, u16* __restrict__ th, u16* __restrict__ tl)
{
  __shared__ float t[32][33];
  const int k0 = blockIdx.x * 32, o0 = blockIdx.y * 32;
  const int r = threadIdx.x >> 3;
  const int c = (threadIdx.x & 7) * 4;
  float4 v = *(const float4*)(w + (size_t)(k0 + r) * 512 + o0 + c);
  t[r][c] = v.x; t[r][c + 1] = v.y; t[r][c + 2] = v.z; t[r][c + 3] = v.w;
  __syncthreads();
  u16x4 hv, lv;
#pragma unroll
  for (int i = 0; i < 4; ++i) {
    float xv = t[c + i][r];
    u16 h = f2bf(xv);
    hv[i] = h; lv[i] = f2bf(xv - b2f(h));
  }
  size_t dst = (size_t)(o0 + r) * 4096 + k0 + c;
  *(u16x4*)(th + dst) = hv;
  *(u16x4*)(tl + dst) = lv;
}

// ---------------------------------------------------------------------------
// OLD split-bf16 MFMA GEMM (128x128, reg-prefetch 2-phase). Kept for x1T only.
// ---------------------------------------------------------------------------
__global__ __launch_bounds__(256) void mfma_split_gemm(
    const u16* __restrict__ Ah, const u16* __restrict__ Al,
    const u16* __restrict__ Bh, const u16* __restrict__ Bl,
    const float* __restrict__ bias, int bias_mode,   // 0 none, 1 per-n, 2 per-m
    u16* __restrict__ Oh, u16* __restrict__ Ol, float* __restrict__ Of,
    int out_f32, int do_elu,
    int K, int lda, int ldb,
    long long Az, long long Bz,
    int msh, long long s_mb, int nsh, long long s_nb, long long s_n,
    long long zb_s, long long zh_s, int zH)
{
  __shared__ u16 As_h[128][40];
  __shared__ u16 As_l[128][40];
  __shared__ u16 Bs_h[128][40];
  __shared__ u16 Bs_l[128][40];
  const int tid = threadIdx.x;
  const int wave = tid >> 6, lane = tid & 63;
  const int wm = (wave >> 1) * 64, wn = (wave & 1) * 64;
  const int bn = blockIdx.x * 128, bm = blockIdx.y * 128;
  const int z = blockIdx.z;
  const u16* Ahb = Ah + (long long)z * Az;
  const u16* Alb = Al + (long long)z * Az;
  const u16* Bhb = Bh + (long long)z * Bz;
  const u16* Blb = Bl + (long long)z * Bz;
  const int lm = lane & 15, lq = lane >> 4;

  const int sr = tid >> 1;
  const int sc = (tid & 1) * 16;
  const size_t ga = (size_t)(bm + sr) * lda + sc;
  const size_t gb = (size_t)(bn + sr) * ldb + sc;

  f32x4 acc[4][4];
#pragma unroll
  for (int i = 0; i < 4; ++i)
#pragma unroll
    for (int j = 0; j < 4; ++j) acc[i][j] = (f32x4){0.0f, 0.0f, 0.0f, 0.0f};

  uint4 r0, r1, r2, r3, r4, r5, r6, r7;
  r0 = *(const uint4*)(Ahb + ga);
  r1 = *(const uint4*)(Ahb + ga + 8);
  r2 = *(const uint4*)(Alb + ga);
  r3 = *(const uint4*)(Alb + ga + 8);
  r4 = *(const uint4*)(Bhb + gb);
  r5 = *(const uint4*)(Bhb + gb + 8);
  r6 = *(const uint4*)(Blb + gb);
  r7 = *(const uint4*)(Blb + gb + 8);

  for (int k0 = 0; k0 < K; k0 += 32) {
    __syncthreads();
    *(uint4*)&As_h[sr][sc] = r0;
    *(uint4*)&As_h[sr][sc + 8] = r1;
    *(uint4*)&As_l[sr][sc] = r2;
    *(uint4*)&As_l[sr][sc + 8] = r3;
    *(uint4*)&Bs_h[sr][sc] = r4;
    *(uint4*)&Bs_h[sr][sc + 8] = r5;
    *(uint4*)&Bs_l[sr][sc] = r6;
    *(uint4*)&Bs_l[sr][sc + 8] = r7;
    __syncthreads();
    int kn = k0 + 32;
    if (kn < K) {
      r0 = *(const uint4*)(Ahb + ga + kn);
      r1 = *(const uint4*)(Ahb + ga + kn + 8);
      r2 = *(const uint4*)(Alb + ga + kn);
      r3 = *(const uint4*)(Alb + ga + kn + 8);
      r4 = *(const uint4*)(Bhb + gb + kn);
      r5 = *(const uint4*)(Bhb + gb + kn + 8);
      r6 = *(const uint4*)(Blb + gb + kn);
      r7 = *(const uint4*)(Blb + gb + kn + 8);
    }
    s16x8 fa_h[4], fa_l[4], fb_h[4], fb_l[4];
#pragma unroll
    for (int t = 0; t < 4; ++t) {
      fa_h[t] = *(const s16x8*)&As_h[wm + t * 16 + lm][lq * 8];
      fa_l[t] = *(const s16x8*)&As_l[wm + t * 16 + lm][lq * 8];
      fb_h[t] = *(const s16x8*)&Bs_h[wn + t * 16 + lm][lq * 8];
      fb_l[t] = *(const s16x8*)&Bs_l[wn + t * 16 + lm][lq * 8];
    }
#pragma unroll
    for (int i = 0; i < 4; ++i)
#pragma unroll
      for (int j = 0; j < 4; ++j) {
        acc[i][j] = __builtin_amdgcn_mfma_f32_16x16x32_bf16(fa_h[i], fb_h[j], acc[i][j], 0, 0, 0);
        acc[i][j] = __builtin_amdgcn_mfma_f32_16x16x32_bf16(fa_h[i], fb_l[j], acc[i][j], 0, 0, 0);
        acc[i][j] = __builtin_amdgcn_mfma_f32_16x16x32_bf16(fa_l[i], fb_h[j], acc[i][j], 0, 0, 0);
      }
  }

  // ---- LDS-transpose epilogue ----
  __syncthreads();
  const long long zoff = (long long)(z / zH) * zb_s + (long long)(z % zH) * zh_s;
  const int mmask = (1 << msh) - 1;
  const int nmask = (1 << nsh) - 1;
  char* lds_raw = (char*)&As_h[0][0] + wave * 4608;
  const int rn = lane >> 2;
  const int rm = (lane & 3) * 16;

  if (out_f32) {
    float* slab = (float*)lds_raw;      // [16][68]
#pragma unroll
    for (int j = 0; j < 4; ++j) {
#pragma unroll
      for (int i = 0; i < 4; ++i) {
        int mb = bm + wm + i * 16 + lq * 4;
        int n = bn + wn + j * 16 + lm;
        f32x4 v = acc[i][j];
        if (bias_mode == 1) v += bias[n];
        else if (bias_mode == 2) { f32x4 b4 = *(const f32x4*)&bias[mb]; v += b4; }
        if (do_elu) {
          v.x = v.x > 0.0f ? v.x : expm1f(v.x);
          v.y = v.y > 0.0f ? v.y : expm1f(v.y);
          v.z = v.z > 0.0f ? v.z : expm1f(v.z);
          v.w = v.w > 0.0f ? v.w : expm1f(v.w);
        }
        *(f32x4*)&slab[lm * 68 + i * 16 + lq * 4] = v;
      }
      __syncthreads();
      int n = bn + wn + j * 16 + rn;
      int mbase = bm + wm + rm;
      long long off = (long long)(mbase >> msh) * s_mb + (mbase & mmask)
                    + (long long)(n >> nsh) * s_nb + (long long)(n & nmask) * s_n + zoff;
      const float* src = &slab[rn * 68 + rm];
      f32x4 v0 = *(const f32x4*)(src + 0);
      f32x4 v1 = *(const f32x4*)(src + 4);
      f32x4 v2 = *(const f32x4*)(src + 8);
      f32x4 v3 = *(const f32x4*)(src + 12);
      *(f32x4*)(Of + off + 0)  = v0;
      *(f32x4*)(Of + off + 4)  = v1;
      *(f32x4*)(Of + off + 8)  = v2;
      *(f32x4*)(Of + off + 12) = v3;
      __syncthreads();
    }
  } else {
    u16* slab_h = (u16*)lds_raw;        // [16][72]
    u16* slab_l = slab_h + 16 * 72;
#pragma unroll
    for (int j = 0; j < 4; ++j) {
#pragma unroll
      for (int i = 0; i < 4; ++i) {
        int mb = bm + wm + i * 16 + lq * 4;
        int n = bn + wn + j * 16 + lm;
        f32x4 v = acc[i][j];
        if (bias_mode == 1) v += bias[n];
        else if (bias_mode == 2) { f32x4 b4 = *(const f32x4*)&bias[mb]; v += b4; }
        if (do_elu) {
          v.x = v.x > 0.0f ? v.x : expm1f(v.x);
          v.y = v.y > 0.0f ? v.y : expm1f(v.y);
          v.z = v.z > 0.0f ? v.z : expm1f(v.z);
          v.w = v.w > 0.0f ? v.w : expm1f(v.w);
        }
        u16 h0 = f2bf(v.x), h1 = f2bf(v.y), h2 = f2bf(v.z), h3 = f2bf(v.w);
        u16x4 hv = {h0, h1, h2, h3};
        u16x4 lv = {f2bf(v.x - b2f(h0)), f2bf(v.y - b2f(h1)),
                    f2bf(v.z - b2f(h2)), f2bf(v.w - b2f(h3))};
        *(u16x4*)&slab_h[lm * 72 + i * 16 + lq * 4] = hv;
        *(u16x4*)&slab_l[lm * 72 + i * 16 + lq * 4] = lv;
      }
      __syncthreads();
      int n = bn + wn + j * 16 + rn;
      int mbase = bm + wm + rm;
      long long off = (long long)(mbase >> msh) * s_mb + (mbase & mmask)
                    + (long long)(n >> nsh) * s_nb + (long long)(n & nmask) * s_n + zoff;
      const u16* sh = &slab_h[rn * 72 + rm];
      const u16* sl = &slab_l[rn * 72 + rm];
      uint4 h0 = *(const uint4*)(sh + 0);
      uint4 h1 = *(const uint4*)(sh + 8);
      uint4 l0 = *(const uint4*)(sl + 0);
      uint4 l1 = *(const uint4*)(sl + 8);
      *(uint4*)(Oh + off + 0) = h0;
      *(uint4*)(Oh + off + 8) = h1;
      *(uint4*)(Ol + off + 0) = l0;
      *(uint4*)(Ol + off + 8) = l1;
      __syncthreads();
    }
  }
}

// ---------------------------------------------------------------------------
// Flat counted-vmcnt split-bf16 GEMM (R2/R3-verified) + R4 changes:
//  * j-phased fragment reads: group1 {all A, B j=0,1} / group2 {B j=2,3},
//    MFMA clusters {j=0,1} / {j=2,3}, sched_barrier(0) pins order so the
//    compiler's own lgkmcnt gating lets cluster-1 MFMAs run while group-2
//    reads drain (breaks the serial LDS-flood -> MFMA-burst pattern).
//  * optional fp32-partial output + z K-slicing (split-K) for G7.
// ---------------------------------------------------------------------------
#define G8_BUF 49152   // 16KB A + 32KB B per buffer, 3 buffers

#define STAGE_A8(T) do { const int _t = (T); if (_t < nt) {                    \
    const int _q = _t % 3;                                                     \
    _Pragma("unroll")                                                          \
    for (int rg_ = 0; rg_ < 2; ++rg_)                                          \
      __builtin_amdgcn_global_load_lds(                                        \
          (const __attribute__((address_space(1))) void*)(gA +                 \
              (size_t)_t * 32 + (size_t)rg_ * 8 * lda),                        \
          (__attribute__((address_space(3))) void*)(ldsAd + _q * G8_BUF +      \
              rg_ * 1024),                                                     \
          16, 0, 0);                                                           \
  } } while (0)

#define STAGE_B8(T) do { const int _t = (T); if (_t < nt) {                    \
    const int _q = _t % 3;                                                     \
    _Pragma("unroll")                                                          \
    for (int rg_ = 0; rg_ < 4; ++rg_)                                          \
      __builtin_amdgcn_global_load_lds(                                        \
          (const __attribute__((address_space(1))) void*)(gB +                 \
              (size_t)_t * 32 + (size_t)rg_ * 8 * ldb),                        \
          (__attribute__((address_space(3))) void*)(ldsBd + _q * G8_BUF +      \
              rg_ * 1024),                                                     \
          16, 0, 0);                                                           \
  } } while (0)

__global__ __launch_bounds__(512, 2) void mfma_split_gemm8(
    const u16* __restrict__ Ah, const u16* __restrict__ Al,
    const u16* __restrict__ Bh, const u16* __restrict__ Bl,
    const float* __restrict__ bias, int bias_mode,   // 0 none, 1 per-n, 2 per-m
    u16* __restrict__ Oh, u16* __restrict__ Ol,
    float* __restrict__ Of, int out_f32,
    int K, int lda, int ldb,
    int msh, long long s_mb, int nsh, long long s_nb, long long s_n,
    int zKS, long long zOs)
{
  __shared__ __align__(128) char ldsb[3 * G8_BUF];   // 144 KB
  const int tid = threadIdx.x;
  const int wave = tid >> 6, lane = tid & 63;
  const int wm = (wave >> 2) * 64, wn = (wave & 3) * 64;
  const int bn = blockIdx.x * 256, bm = blockIdx.y * 128;
  const int z = blockIdx.z;
  const int lm = lane & 15, lq = lane >> 4;
  const int nt = K >> 5;

  // staging geometry: lane -> (row srow, phys slot); logical slot = phys ^ row
  const int srow = lane >> 3;
  const int sl = (lane & 7) ^ srow;          // logical slot this lane feeds
  const int scol = (sl & 3) * 8;             // k-offset (u16) within tile
  const u16* Asel = (sl < 4) ? Ah : Al;
  const u16* Bsel = (sl < 4) ? Bh : Bl;

  // hoisted per-wave staging bases (z K-slice offset for split-K)
  const u16* gA = Asel + (size_t)(bm + wave * 16 + srow) * lda + scol + (size_t)z * zKS;
  const u16* gB = Bsel + (size_t)(bn + wave * 32 + srow) * ldb + scol + (size_t)z * zKS;
  char* ldsAd = ldsb + wave * 2048;            // A rows wave*16.., lane*16 added by HW
  char* ldsBd = ldsb + 16384 + wave * 4096;    // B rows wave*32..

  // read geometry: frag row r has r&7 == lm&7; hi slot lq -> phys lq^(lm&7)
  const int hbyt = (lq ^ (lm & 7)) * 16;
  const int lbyt = hbyt ^ 64;

  f32x4 acc[4][4];
#pragma unroll
  for (int i = 0; i < 4; ++i)
#pragma unroll
    for (int j = 0; j < 4; ++j) acc[i][j] = (f32x4){0.0f, 0.0f, 0.0f, 0.0f};

  // prologue: stage tiles 0 and 1 (FIFO: tile0's 6 loads first)
  STAGE_A8(0); STAGE_B8(0);
  STAGE_A8(1); STAGE_B8(1);
  if (nt > 1) asm volatile("s_waitcnt vmcnt(6)" ::: "memory");
  else        asm volatile("s_waitcnt vmcnt(0)" ::: "memory");
  __builtin_amdgcn_s_barrier();
  __builtin_amdgcn_sched_barrier(0);

#pragma unroll 3
  for (int t = 0; t < nt; ++t) {
    const int q = t % 3;
    // issue next-next tile's staging first (HBM latency hiding)
    STAGE_A8(t + 2);
    STAGE_B8(t + 2);
    const char* Abase = ldsb + q * G8_BUF + (wm + lm) * 128;
    const char* Bbase = ldsb + q * G8_BUF + 16384 + (wn + lm) * 128;
    s16x8 fa[4][2], fb[4][2];
    // read group 1: all A frags + B j=0,1 (12 ds_read_b128)
#pragma unroll
    for (int i = 0; i < 4; ++i) {
      fa[i][0] = *(const s16x8*)(Abase + i * 2048 + hbyt);
      fa[i][1] = *(const s16x8*)(Abase + i * 2048 + lbyt);
    }
#pragma unroll
    for (int j = 0; j < 2; ++j) {
      fb[j][0] = *(const s16x8*)(Bbase + j * 2048 + hbyt);
      fb[j][1] = *(const s16x8*)(Bbase + j * 2048 + lbyt);
    }
    __builtin_amdgcn_sched_barrier(0);
    // read group 2: B j=2,3 (4 ds_read_b128) -- drains behind cluster 1
#pragma unroll
    for (int j = 2; j < 4; ++j) {
      fb[j][0] = *(const s16x8*)(Bbase + j * 2048 + hbyt);
      fb[j][1] = *(const s16x8*)(Bbase + j * 2048 + lbyt);
    }
    __builtin_amdgcn_sched_barrier(0);
    // MFMA cluster 1: j=0,1 (gated by compiler lgkmcnt(4) on group-1 reads)
    __builtin_amdgcn_s_setprio(1);
#pragma unroll
    for (int j = 0; j < 2; ++j)
#pragma unroll
      for (int i = 0; i < 4; ++i) {
        acc[i][j] = __builtin_amdgcn_mfma_f32_16x16x32_bf16(fa[i][0], fb[j][0], acc[i][j], 0, 0, 0);
        acc[i][j] = __builtin_amdgcn_mfma_f32_16x16x32_bf16(fa[i][0], fb[j][1], acc[i][j], 0, 0, 0);
        acc[i][j] = __builtin_amdgcn_mfma_f32_16x16x32_bf16(fa[i][1], fb[j][0], acc[i][j], 0, 0, 0);
      }
    __builtin_amdgcn_s_setprio(0);
    __builtin_amdgcn_sched_barrier(0);
    // MFMA cluster 2: j=2,3
    __builtin_amdgcn_s_setprio(1);
#pragma unroll
    for (int j = 2; j < 4; ++j)
#pragma unroll
      for (int i = 0; i < 4; ++i) {
        acc[i][j] = __builtin_amdgcn_mfma_f32_16x16x32_bf16(fa[i][0], fb[j][0], acc[i][j], 0, 0, 0);
        acc[i][j] = __builtin_amdgcn_mfma_f32_16x16x32_bf16(fa[i][0], fb[j][1], acc[i][j], 0, 0, 0);
        acc[i][j] = __builtin_amdgcn_mfma_f32_16x16x32_bf16(fa[i][1], fb[j][0], acc[i][j], 0, 0, 0);
      }
    __builtin_amdgcn_s_setprio(0);
    if (t + 1 < nt) {
      if (t + 2 < nt) asm volatile("s_waitcnt vmcnt(6)" ::: "memory");
      else            asm volatile("s_waitcnt vmcnt(0)" ::: "memory");
      __builtin_amdgcn_s_barrier();
      __builtin_amdgcn_sched_barrier(0);
    }
  }

  // ---- LDS-transpose epilogue ----
  __syncthreads();
  const long long zoff = (long long)z * zOs;
  const int mmask = (1 << msh) - 1;
  const int nmask = (1 << nsh) - 1;
  char* lds_raw = ldsb + wave * 4608;
  const int rn = lane >> 2;
  const int rm = (lane & 3) * 16;

  if (out_f32) {
    float* slab = (float*)lds_raw;      // [16][68]
#pragma unroll
    for (int j = 0; j < 4; ++j) {
#pragma unroll
      for (int i = 0; i < 4; ++i) {
        int mb = bm + wm + i * 16 + lq * 4;
        int n = bn + wn + j * 16 + lm;
        f32x4 v = acc[i][j];
        if (bias_mode == 1) v += bias[n];
        else if (bias_mode == 2) { f32x4 b4 = *(const f32x4*)&bias[mb]; v += b4; }
        *(f32x4*)&slab[lm * 68 + i * 16 + lq * 4] = v;
      }
      __syncthreads();
      int n = bn + wn + j * 16 + rn;
      int mbase = bm + wm + rm;
      long long off = (long long)(mbase >> msh) * s_mb + (mbase & mmask)
                    + (long long)(n >> nsh) * s_nb + (long long)(n & nmask) * s_n + zoff;
      const float* src = &slab[rn * 68 + rm];
      f32x4 v0 = *(const f32x4*)(src + 0);
      f32x4 v1 = *(const f32x4*)(src + 4);
      f32x4 v2 = *(const f32x4*)(src + 8);
      f32x4 v3 = *(const f32x4*)(src + 12);
      *(f32x4*)(Of + off + 0)  = v0;
      *(f32x4*)(Of + off + 4)  = v1;
      *(f32x4*)(Of + off + 8)  = v2;
      *(f32x4*)(Of + off + 12) = v3;
      __syncthreads();
    }
  } else {
    u16* slab_h = (u16*)lds_raw;        // [16][72]
    u16* slab_l = slab_h + 16 * 72;
#pragma unroll
    for (int j = 0; j < 4; ++j) {
#pragma unroll
      for (int i = 0; i < 4; ++i) {
        int mb = bm + wm + i * 16 + lq * 4;
        int n = bn + wn + j * 16 + lm;
        f32x4 v = acc[i][j];
        if (bias_mode == 1) v += bias[n];
        else if (bias_mode == 2) { f32x4 b4 = *(const f32x4*)&bias[mb]; v += b4; }
        u16 h0 = f2bf(v.x), h1 = f2bf(v.y), h2 = f2bf(v.z), h3 = f2bf(v.w);
        u16x4 hv = {h0, h1, h2, h3};
        u16x4 lv = {f2bf(v.x - b2f(h0)), f2bf(v.y - b2f(h1)),
                    f2bf(v.z - b2f(h2)), f2bf(v.w - b2f(h3))};
        *(u16x4*)&slab_h[lm * 72 + i * 16 + lq * 4] = hv;
        *(u16x4*)&slab_l[lm * 72 + i * 16 + lq * 4] = lv;
      }
      __syncthreads();
      int n = bn + wn + j * 16 + rn;
      int mbase = bm + wm + rm;
      long long off = (long long)(mbase >> msh) * s_mb + (mbase & mmask)
                    + (long long)(n >> nsh) * s_nb + (long long)(n & nmask) * s_n + zoff;
      const u16* sh = &slab_h[rn * 72 + rm];
      const u16* slp = &slab_l[rn * 72 + rm];
      uint4 h0 = *(const uint4*)(sh + 0);
      uint4 h1 = *(const uint4*)(sh + 8);
      uint4 l0 = *(const uint4*)(slp + 0);
      uint4 l1 = *(const uint4*)(slp + 8);
      *(uint4*)(Oh + off + 0) = h0;
      *(uint4*)(Oh + off + 8) = h1;
      *(uint4*)(Ol + off + 0) = l0;
      *(uint4*)(Ol + off + 8) = l1;
      __syncthreads();
    }
  }
}

// ---------------------------------------------------------------------------
// Split-K reduce for G7 (8 slices).
// ---------------------------------------------------------------------------
__global__ __launch_bounds__(256) void reduce8_bias(
    const float* __restrict__ ps, const float* __restrict__ bias,
    float* __restrict__ h2T, int col0)
{
  int base = (blockIdx.x * 256 + threadIdx.x) * 4;   // 512*2048 elements
  int o = base >> 11, m = base & 2047;
  f32x4 v = *(const f32x4*)(ps + base);
#pragma unroll
  for (int s = 1; s < 8; ++s)
    v += *(const f32x4*)(ps + base + (size_t)s * 1048576);
  v += bias[o];
  *(f32x4*)(h2T + (size_t)o * 8192 + col0 + m) = v;
}

// ---------------------------------------------------------------------------
// esrc/edst from hT (split bf16): block per (bc,head), 512 threads.
// ---------------------------------------------------------------------------
__global__ __launch_bounds__(512) void dot_pairs_hT(
    const u16* __restrict__ hTh, const u16* __restrict__ hTl,
    const float* __restrict__ W,   // ha_w [8][1024]
    float* __restrict__ esrc, float* __restrict__ edst)
{
  int bh = blockIdx.x;
  int head = bh & 7;
  int tid = threadIdx.x;
  int os = tid >> 7, i = tid & 127;
  const u16* ph = hTh + (size_t)bh * 65536 + (size_t)os * 16384 + i;
  const u16* pl = hTl + (size_t)bh * 65536 + (size_t)os * 16384 + i;
  const float* w1 = W + head * 1024 + os * 128;
  float s1 = 0.0f, s2 = 0.0f;
#pragma unroll 8
  for (int o = 0; o < 128; ++o) {
    float hv = b2f(ph[o * 128]) + b2f(pl[o * 128]);
    s1 = fmaf(hv, w1[o], s1);
    s2 = fmaf(hv, w1[512 + o], s2);
  }
  __shared__ float sh1[4][128], sh2[4][128];
  sh1[os][i] = s1;
  sh2[os][i] = s2;
  __syncthreads();
  if (os == 0) {
    esrc[bh * 128 + i] = sh1[0][i] + sh1[1][i] + sh1[2][i] + sh1[3][i];
    edst[bh * 128 + i] = sh2[0][i] + sh2[1][i] + sh2[2][i] + sh2[3][i];
  }
}

// e2 dots from h2T (fp32): block per b, 512 threads.
__global__ __launch_bounds__(512) void dot_pairs_h2T(
    const float* __restrict__ h2T, const float* __restrict__ oa,
    float* __restrict__ e2s, float* __restrict__ e2d)
{
  int b = blockIdx.x;
  int tid = threadIdx.x;
  int os = tid >> 7, i = tid & 127;
  const float* hb = h2T + (size_t)os * 128 * 8192 + b * 128 + i;
  const float* oa1 = oa + os * 128;
  float s1 = 0.0f, s2 = 0.0f;
#pragma unroll 8
  for (int o = 0; o < 128; ++o) {
    float hv = hb[(size_t)o * 8192];
    s1 = fmaf(hv, oa1[o], s1);
    s2 = fmaf(hv, oa1[512 + o], s2);
  }
  __shared__ float sh1[4][128], sh2[4][128];
  sh1[os][i] = s1;
  sh2[os][i] = s2;
  __syncthreads();
  if (os == 0) {
    e2s[b * 128 + i] = sh1[0][i] + sh1[1][i] + sh1[2][i] + sh1[3][i];
    e2d[b * 128 + i] = sh2[0][i] + sh2[1][i] + sh2[2][i] + sh2[3][i];
  }
}

// ---------------------------------------------------------------------------
// Edge softmax; 4 rows per 256-thread block (one row per wave).
// split=1 -> bf16 hi/lo output, else fp32.  adj pre-offset.
// ---------------------------------------------------------------------------
__global__ __launch_bounds__(256) void edge_softmax_kernel(
    const float* __restrict__ esrc, const float* __restrict__ edst,
    const float* __restrict__ bias, const float* __restrict__ adj,
    float* __restrict__ attf, u16* __restrict__ atth, u16* __restrict__ attl,
    int H, int split)
{
  int row = blockIdx.x * 4 + (threadIdx.x >> 6);
  int lane = threadIdx.x & 63;
  int i = row & 127;
  int bh = row >> 7;
  int hd = bh % H;
  int b = bh / H;
  float es = esrc[row] + bias[hd];
  const float* adjr = adj + ((size_t)b * N_ + i) * N_;
  const float* edr = edst + (size_t)bh * N_;
  float v[2];
#pragma unroll
  for (int t = 0; t < 2; ++t) {
    int j = lane + t * 64;
    float e = es + edr[j];
    e = (e >= 0.0f) ? e : 0.2f * e;
    v[t] = (adjr[j] > 0.0f) ? e : NEG_E_;
  }
  float mx = fmaxf(v[0], v[1]);
  for (int off = 32; off; off >>= 1) mx = fmaxf(mx, __shfl_xor(mx, off));
  float e0 = expf(v[0] - mx), e1 = expf(v[1] - mx);
  float sm = e0 + e1;
  for (int off = 32; off; off >>= 1) sm += __shfl_xor(sm, off);
  float inv = 1.0f / sm;
  float p0 = e0 * inv, p1 = e1 * inv;
  size_t base = (size_t)row * N_;
  if (split) {
    u16 h0 = f2bf(p0), h1 = f2bf(p1);
    atth[base + lane] = h0;
    attl[base + lane] = f2bf(p0 - b2f(h0));
    atth[base + lane + 64] = h1;
    attl[base + lane + 64] = f2bf(p1 - b2f(h1));
  } else {
    attf[base + lane] = p0;
    attf[base + lane + 64] = p1;
  }
}

// ---------------------------------------------------------------------------
// Stage-2 fp32 batched GEMM + ELU (h2T[512][8192] B-layout).
// ---------------------------------------------------------------------------
__global__ __launch_bounds__(256) void bgemm_elu_bt_f32(
    const float* __restrict__ A, const float* __restrict__ BT,
    float* __restrict__ C)
{
  __shared__ float As[16][64];
  __shared__ float Bs[16][68];
  const int tid = threadIdx.x;
  const int tm = blockIdx.x >> 3, tn = blockIdx.x & 7;
  const int bm = tm * 64, bn = tn * 64;
  const int b = blockIdx.y;
  const float* Ab = A + (size_t)b * 16384;
  const float* BTb = BT + (size_t)b * 128;
  const int ty = tid >> 4, tx = tid & 15;
  const int ar = tid >> 2, ac = (tid & 3) * 4;
  float acc[4][4];
#pragma unroll
  for (int i = 0; i < 4; ++i)
#pragma unroll
    for (int j = 0; j < 4; ++j) acc[i][j] = 0.0f;

  for (int k0 = 0; k0 < 128; k0 += 16) {
    float4 av = *(const float4*)(Ab + (size_t)(bm + ar) * 128 + k0 + ac);
    float4 bv = *(const float4*)(BTb + (size_t)(bn + ar) * 8192 + k0 + ac);
    __syncthreads();
    As[ac + 0][ar] = av.x; As[ac + 1][ar] = av.y; As[ac + 2][ar] = av.z; As[ac + 3][ar] = av.w;
    Bs[ac + 0][ar] = bv.x; Bs[ac + 1][ar] = bv.y; Bs[ac + 2][ar] = bv.z; Bs[ac + 3][ar] = bv.w;
    __syncthreads();
#pragma unroll
    for (int kk = 0; kk < 16; ++kk) {
      float a[4], bb[4];
      *(float4*)a  = *(const float4*)&As[kk][ty * 4];
      *(float4*)bb = *(const float4*)&Bs[kk][tx * 4];
#pragma unroll
      for (int i = 0; i < 4; ++i)
#pragma unroll
        for (int j = 0; j < 4; ++j)
          acc[i][j] = fmaf(a[i], bb[j], acc[i][j]);
    }
  }
#pragma unroll
  for (int i = 0; i < 4; ++i) {
    int row = b * 128 + bm + ty * 4 + i;
    float4 v;
    v.x = acc[i][0] > 0.0f ? acc[i][0] : expm1f(acc[i][0]);
    v.y = acc[i][1] > 0.0f ? acc[i][1] : expm1f(acc[i][1]);
    v.z = acc[i][2] > 0.0f ? acc[i][2] : expm1f(acc[i][2]);
    v.w = acc[i][3] > 0.0f ? acc[i][3] : expm1f(acc[i][3]);
    *(float4*)(C + (size_t)row * 512 + bn + tx * 4) = v;
  }
}

// ---------------------------------------------------------------------------
// logits = x2 @ fin_w + fin_b  (one wave per row)
// ---------------------------------------------------------------------------
__global__ __launch_bounds__(256) void logits_kernel(
    const float* __restrict__ X, const float* __restrict__ w,
    const float* __restrict__ bptr, float* __restrict__ out, int R)
{
  int wv = (blockIdx.x * 256 + threadIdx.x) >> 6;
  int lane = threadIdx.x & 63;
  if (wv >= R) return;
  const float* xr = X + (size_t)wv * 512;
  float s = 0.0f;
#pragma unroll
  for (int i = 0; i < 8; ++i) {
    int c = lane + i * 64;
    s = fmaf(xr[c], w[c], s);
  }
  for (int off = 32; off; off >>= 1) s += __shfl_down(s, off);
  if (lane == 0) out[wv] = s + bptr[0];
}

// ---------------------------------------------------------------------------
// Final: scores -> stable rank -> gather fix -> expand.
// ---------------------------------------------------------------------------
__global__ __launch_bounds__(128) void finalize_kernel(
    const float* __restrict__ logits, const float* __restrict__ tag,
    const float* __restrict__ amask, const int* __restrict__ ig,
    int* __restrict__ out)
{
  const int b = blockIdx.x, tid = threadIdx.x;
  __shared__ float red[N_];
  __shared__ float scs[N_];
  __shared__ int fs[N_], fe[N_], lens[N_], csum[N_];
  __shared__ int redi[N_];

  float lg = logits[b * N_ + tid];
  float tg = tag[b * N_ + tid];
  float am = amask[b * N_ + tid];
  float m = (tg > 0.0f) ? am : 0.0f;

  float in1 = (m > 0.0f) ? lg * m : NEG_S_;
  red[tid] = in1; __syncthreads();
  for (int s = 64; s > 0; s >>= 1) { if (tid < s) red[tid] = fmaxf(red[tid], red[tid + s]); __syncthreads(); }
  float M1 = red[0]; __syncthreads();
  float e1 = expf(in1 - M1);
  red[tid] = e1; __syncthreads();
  for (int s = 64; s > 0; s >>= 1) { if (tid < s) red[tid] += red[tid + s]; __syncthreads(); }
  float S1 = red[0]; __syncthreads();
  float sc = e1 / S1;

  red[tid] = m; __syncthreads();
  for (int s = 64; s > 0; s >>= 1) { if (tid < s) red[tid] += red[tid + s]; __syncthreads(); }
  float SM = red[0]; __syncthreads();

  float in2 = (m > 0.0f) ? ((float)(N_ - tid) / SM) * m : NEG_S_;
  red[tid] = in2; __syncthreads();
  for (int s = 64; s > 0; s >>= 1) { if (tid < s) red[tid] = fmaxf(red[tid], red[tid + s]); __syncthreads(); }
  float M2 = red[0]; __syncthreads();
  float e2 = expf(in2 - M2);
  red[tid] = e2; __syncthreads();
  for (int s = 64; s > 0; s >>= 1) { if (tid < s) red[tid] += red[tid + s]; __syncthreads(); }
  float S2 = red[0]; __syncthreads();
  float ii = e2 / S2;

  scs[tid] = sc + ii;
  __syncthreads();

  float si = scs[tid];
  int rank = 0;
  for (int j = 0; j < N_; ++j) {
    float sj = scs[j];
    rank += (sj > si) || (sj == si && j < tid);
  }
  fs[tid] = ig[(b * N_ + rank) * 2 + 0];
  fe[tid] = ig[(b * N_ + rank) * 2 + 1];
  __syncthreads();

  redi[tid] = (fs[tid] == 0 && fe[tid] == 0) ? tid : N_;
  __syncthreads();
  for (int s = 64; s > 0; s >>= 1) { if (tid < s) redi[tid] = min(redi[tid], redi[tid + s]); __syncthreads(); }
  int fz = redi[0]; __syncthreads();
  lens[tid] = (tid < fz) ? (fe[tid] - fs[tid]) : 0;
  __syncthreads();
  if (tid == 0) {
    int r = 0;
    for (int k = 0; k < N_; ++k) { r += lens[k]; csum[k] = r; }
  }
  __syncthreads();
  int total = csum[N_ - 1];
  int l = tid;
  int k = 0;
  while (k < N_ && csum[k] <= l) ++k;
  if (k > N_ - 1) k = N_ - 1;
  int val = fs[k] + (l - (csum[k] - lens[k]));
  out[b * N_ + l] = (l < total) ? val : l;
}

// ---------------------------------------------------------------------------
extern "C" void kernel_launch(void* const* d_in, const int* in_sizes, int n_in,
                              void* d_out, int out_size, void* d_ws, size_t ws_size,
                              hipStream_t stream)
{
  const float* x     = (const float*)d_in[0];
  const float* tag   = (const float*)d_in[1];
  const int*   offs  = (const int*)  d_in[2];
  const float* amask = (const float*)d_in[3];
  const float* adj   = (const float*)d_in[4];
  const float* Wg_w  = (const float*)d_in[5];
  const float* Wg_b  = (const float*)d_in[6];
  const float* hW_w  = (const float*)d_in[7];
  const float* hW_b  = (const float*)d_in[8];
  const float* ha_w  = (const float*)d_in[9];
  const float* ha_b  = (const float*)d_in[10];
  const float* oW_w  = (const float*)d_in[11];
  const float* oW_b  = (const float*)d_in[12];
  const float* oa_w  = (const float*)d_in[13];
  const float* oa_b  = (const float*)d_in[14];
  const float* fin_w = (const float*)d_in[15];
  const float* fin_b = (const float*)d_in[16];
  int* out = (int*)d_out;

  // ---- workspace: 154.5 MB (< proven-safe 197.5 MB) ----
  char* ws = (char*)d_ws;
  size_t o = 0;
  int* ig     = (int*)(ws + o);  o += 131072;
  u16* WgT_h  = (u16*)(ws + o);  o += 1572864;
  u16* WgT_l  = (u16*)(ws + o);  o += 1572864;
  u16* hWT_h  = (u16*)(ws + o);  o += 8388608;
  u16* hWT_l  = (u16*)(ws + o);  o += 8388608;
  u16* oWT_h  = (u16*)(ws + o);  o += 4194304;
  u16* oWT_l  = (u16*)(ws + o);  o += 4194304;
  float* h2T  = (float*)(ws + o); o += 16777216;
  float* esrc = (float*)(ws + o); o += 65536;
  float* edst = (float*)(ws + o); o += 65536;
  float* e2s  = (float*)(ws + o); o += 32768;
  float* e2d  = (float*)(ws + o); o += 32768;
  float* lgts = (float*)(ws + o); o += 32768;
  u16* xw_h   = (u16*)(ws + o);  o += 16777216;   // full-batch xw (8192x1024)
  u16* xw_l   = (u16*)(ws + o);  o += 16777216;
  char* pool  = ws + o;          o += 75497472;   // overlaid region

  // pool overlays (time-sliced):
  u16* xoff_h = (u16*)(pool + 0);          // full-batch x_off (8192x768), dead after G2
  u16* xoff_l = (u16*)(pool + 12582912);
  u16* hT_h   = (u16*)(pool + 0);          // per-chunk hT (dead after x1T)
  u16* hT_l   = (u16*)(pool + 16777216);
  u16* x1_h   = (u16*)(pool + 33554432);   // per-chunk x1
  u16* x1_l   = (u16*)(pool + 50331648);
  u16* att_h  = (u16*)(pool + 67108864);   // per-chunk att
  u16* att_l  = (u16*)(pool + 71303168);
  float* ps   = (float*)(pool + 0);        // G7 split-K partials (8x4MiB, overlays dead hT)
  float* att2 = (float*)(pool + 0);        // stage-2 tail
  float* x2   = (float*)(pool + 4194304);

  // weight packing (LDS-tiled transpose, coalesced both sides)
  pack_wgT<<<dim3(24, 32), 256, 0, stream>>>(Wg_w, WgT_h, WgT_l);
  pack_hwT<<<dim3(16, 32, 8), 256, 0, stream>>>(hW_w, hWT_h, hWT_l);
  pack_owT<<<dim3(128, 16), 256, 0, stream>>>(oW_w, oWT_h, oWT_l);

  // full-batch group pool -> x_off (split), ig
  group_pool_kernel<<<dim3(B_, 6), 256, 0, stream>>>(x, offs, xoff_h, xoff_l, ig);

  // G2 full-batch (swapped): xw[node][feat] = x_off @ Wg + Wg_b.
  // M=1024(feat), N=8192(node), K=768.  grid 32x8 = 256.
  mfma_split_gemm8<<<dim3(32, 8, 1), 512, 0, stream>>>(
      WgT_h, WgT_l, xoff_h, xoff_l, Wg_b, 2,
      xw_h, xw_l, nullptr, 0,
      768, 768, 768,
      10, 0, 13, 0, 1024, 0, 0);

  for (int b0 = 0; b0 < B_; b0 += CHUNK_) {
    // G3: hT[(bc*8+h)*512+o][i] = (xw @ hW + hW_b)^T. M=2048,N=4096,K=1024.
    // grid 16x16 = 256 blocks.
    mfma_split_gemm8<<<dim3(16, 16, 1), 512, 0, stream>>>(
        xw_h + (size_t)b0 * 131072, xw_l + (size_t)b0 * 131072,
        hWT_h, hWT_l, hW_b, 1,
        hT_h, hT_l, nullptr, 0,
        1024, 1024, 1024,
        7, 524288, 9, 65536, 128, 0, 0);

    dot_pairs_hT<<<CHUNK_ * 8, 512, 0, stream>>>(hT_h, hT_l, ha_w, esrc, edst);
    edge_softmax_kernel<<<CHUNK_ * 8 * 32, 256, 0, stream>>>(
        esrc, edst, ha_b, adj + (size_t)b0 * 16384, nullptr, att_h, att_l, 8, 1);

    // x1T: per z=(bc,h): M=512(o),N=128(i),K=128(j)
    mfma_split_gemm<<<dim3(1, 4, CHUNK_ * 8), 256, 0, stream>>>(
        hT_h, hT_l, att_h, att_l, nullptr, 0,
        x1_h, x1_l, nullptr, 0, 1,
        128, 128, 128, 65536, 16384,
        9, 0, 7, 0, 4096, 524288, 512, 8);

    // G7 via gemm8, split-K=8: M=2048,N=512, K-slice=512 (ps overlays dead hT)
    mfma_split_gemm8<<<dim3(2, 16, 8), 512, 0, stream>>>(
        x1_h, x1_l, oWT_h, oWT_l, nullptr, 0,
        nullptr, nullptr, ps, 1,
        512, 4096, 4096,
        13, 0, 9, 0, 2048, 512, 1048576);
    reduce8_bias<<<1024, 256, 0, stream>>>(ps, oW_b, h2T, b0 * 128);
  }

  // attention-2 (fp32, unchunked)
  dot_pairs_h2T<<<64, 512, 0, stream>>>(h2T, oa_w, e2s, e2d);
  edge_softmax_kernel<<<2048, 256, 0, stream>>>(e2s, e2d, oa_b, adj,
      att2, nullptr, nullptr, 1, 0);
  bgemm_elu_bt_f32<<<dim3(16, 64), 256, 0, stream>>>(att2, h2T, x2);

  // logits + finalize
  logits_kernel<<<2048, 256, 0, stream>>>(x2, fin_w, fin_b, lgts, 8192);
  finalize_kernel<<<B_, 128, 0, stream>>>(lgts, tag, amask, ig, out);
}